// Round 1
// baseline (597.612 us; speedup 1.0000x reference)
//
#include <hip/hip_runtime.h>
#include <hip/hip_bf16.h>
#include <math.h>

#define B_  64
#define S_  128
#define E_  512
#define H_  1024
#define V_  32000
#define H3_ 3072
#define NT_ 16   // H_/64 n-tiles in energy kernel

// ---------------------------------------------------------------------------
// Generic C[M,N] = (acc ? C : 0) + A[M,K] @ W[N,K]^T (+ bias[N])
// M is always 64 here (gridDim.y == 1). Tile 64x64, 256 threads, 4x4/thread.
// LDS tiles stored K-major-transposed (As[k][m]) so fragment reads are b128.
// ---------------------------------------------------------------------------
__global__ void gemm_nt(const float* __restrict__ A, const float* __restrict__ W,
                        const float* __restrict__ bias, float* __restrict__ C,
                        int N, int K, int ldw, int woff, int accumulate) {
    __shared__ float As[16][64];
    __shared__ float Ws[16][64];
    const int n0 = blockIdx.x * 64;
    const int t  = threadIdx.x;
    const int tx = t & 15, ty = t >> 4;
    const int lm = t >> 2;          // 0..63 (tile row)
    const int lk = (t & 3) * 4;     // 0,4,8,12

    float c[4][4];
    #pragma unroll
    for (int i = 0; i < 4; ++i)
        #pragma unroll
        for (int j = 0; j < 4; ++j) c[i][j] = 0.f;

    for (int k0 = 0; k0 < K; k0 += 16) {
        float4 av = *(const float4*)&A[lm * K + k0 + lk];
        float4 wv = *(const float4*)&W[(n0 + lm) * ldw + woff + k0 + lk];
        As[lk + 0][lm] = av.x; As[lk + 1][lm] = av.y;
        As[lk + 2][lm] = av.z; As[lk + 3][lm] = av.w;
        Ws[lk + 0][lm] = wv.x; Ws[lk + 1][lm] = wv.y;
        Ws[lk + 2][lm] = wv.z; Ws[lk + 3][lm] = wv.w;
        __syncthreads();
        #pragma unroll
        for (int k = 0; k < 16; ++k) {
            float4 a = *(const float4*)&As[k][ty * 4];
            float4 w = *(const float4*)&Ws[k][tx * 4];
            c[0][0] += a.x * w.x; c[0][1] += a.x * w.y; c[0][2] += a.x * w.z; c[0][3] += a.x * w.w;
            c[1][0] += a.y * w.x; c[1][1] += a.y * w.y; c[1][2] += a.y * w.z; c[1][3] += a.y * w.w;
            c[2][0] += a.z * w.x; c[2][1] += a.z * w.y; c[2][2] += a.z * w.z; c[2][3] += a.z * w.w;
            c[3][0] += a.w * w.x; c[3][1] += a.w * w.y; c[3][2] += a.w * w.z; c[3][3] += a.w * w.w;
        }
        __syncthreads();
    }

    #pragma unroll
    for (int i = 0; i < 4; ++i) {
        const int m = ty * 4 + i;
        #pragma unroll
        for (int j = 0; j < 4; ++j) {
            const int n = n0 + tx * 4 + j;
            float val = c[i][j];
            if (bias) val += bias[n];
            if (accumulate) val += C[m * N + n];
            C[m * N + n] = val;
        }
    }
}

// ---------------------------------------------------------------------------
// Energy GEMM fused with tanh + v-weighted reduce:
// for one s (blockIdx.y) and one 64-wide h-tile (blockIdx.x):
//   e[b][h] = tanh( enc[s,b,:] . Wa2[h,:] + hproj[b][h] )   (hproj includes ba)
//   partials[b][s][nt] = sum_{h in tile} v[h] * e[b][h]
// ---------------------------------------------------------------------------
__global__ void energy_scores(const float* __restrict__ enc, const float* __restrict__ Wa,
                              const float* __restrict__ hproj, const float* __restrict__ v,
                              float* __restrict__ partials) {
    __shared__ float As[16][64];
    __shared__ float Ws[16][64];
    __shared__ float red[64][16];
    const int nt = blockIdx.x;          // 0..15
    const int s  = blockIdx.y;          // 0..127
    const int n0 = nt * 64;
    const float* Arow = enc + (size_t)s * (B_ * H_);   // [64,1024] block (b rows)
    const int t  = threadIdx.x;
    const int tx = t & 15, ty = t >> 4;
    const int lm = t >> 2;
    const int lk = (t & 3) * 4;

    float c[4][4];
    #pragma unroll
    for (int i = 0; i < 4; ++i)
        #pragma unroll
        for (int j = 0; j < 4; ++j) c[i][j] = 0.f;

    for (int k0 = 0; k0 < H_; k0 += 16) {
        float4 av = *(const float4*)&Arow[lm * H_ + k0 + lk];
        float4 wv = *(const float4*)&Wa[(size_t)(n0 + lm) * (2 * H_) + H_ + k0 + lk];
        As[lk + 0][lm] = av.x; As[lk + 1][lm] = av.y;
        As[lk + 2][lm] = av.z; As[lk + 3][lm] = av.w;
        Ws[lk + 0][lm] = wv.x; Ws[lk + 1][lm] = wv.y;
        Ws[lk + 2][lm] = wv.z; Ws[lk + 3][lm] = wv.w;
        __syncthreads();
        #pragma unroll
        for (int k = 0; k < 16; ++k) {
            float4 a = *(const float4*)&As[k][ty * 4];
            float4 w = *(const float4*)&Ws[k][tx * 4];
            c[0][0] += a.x * w.x; c[0][1] += a.x * w.y; c[0][2] += a.x * w.z; c[0][3] += a.x * w.w;
            c[1][0] += a.y * w.x; c[1][1] += a.y * w.y; c[1][2] += a.y * w.z; c[1][3] += a.y * w.w;
            c[2][0] += a.z * w.x; c[2][1] += a.z * w.y; c[2][2] += a.z * w.z; c[2][3] += a.z * w.w;
            c[3][0] += a.w * w.x; c[3][1] += a.w * w.y; c[3][2] += a.w * w.z; c[3][3] += a.w * w.w;
        }
        __syncthreads();
    }

    // epilogue: tanh + v-reduce over this h-tile
    #pragma unroll
    for (int i = 0; i < 4; ++i) {
        const int b = ty * 4 + i;
        float part = 0.f;
        #pragma unroll
        for (int j = 0; j < 4; ++j) {
            const int h = n0 + tx * 4 + j;
            float e = tanhf(c[i][j] + hproj[b * H_ + h]);
            part += v[h] * e;
        }
        red[b][tx] = part;
    }
    __syncthreads();
    if (t < 64) {
        float sum = 0.f;
        #pragma unroll
        for (int x = 0; x < 16; ++x) sum += red[t][x];
        partials[((size_t)t * S_ + s) * NT_ + nt] = sum;
    }
}

// ---------------------------------------------------------------------------
// Per-b softmax over S=128 scores (sum of 16 partials each) -> attn weights
// ---------------------------------------------------------------------------
__global__ void softmax_attn(const float* __restrict__ partials, float* __restrict__ attn_out) {
    __shared__ float red[128];
    const int b = blockIdx.x;
    const int s = threadIdx.x;      // 0..127
    float sc = 0.f;
    #pragma unroll
    for (int nt = 0; nt < NT_; ++nt) sc += partials[((size_t)b * S_ + s) * NT_ + nt];

    red[s] = sc; __syncthreads();
    for (int o = 64; o > 0; o >>= 1) {
        if (s < o) red[s] = fmaxf(red[s], red[s + o]);
        __syncthreads();
    }
    const float mx = red[0]; __syncthreads();
    const float e = expf(sc - mx);
    red[s] = e; __syncthreads();
    for (int o = 64; o > 0; o >>= 1) {
        if (s < o) red[s] += red[s + o];
        __syncthreads();
    }
    attn_out[b * S_ + s] = e / red[0];
}

// ---------------------------------------------------------------------------
// context[b][h] = sum_s attn[b][s] * enc[s][b][h]
// ---------------------------------------------------------------------------
__global__ void context_k(const float* __restrict__ attn, const float* __restrict__ enc,
                          float* __restrict__ ctx) {
    __shared__ float aw[S_];
    const int b = blockIdx.y;
    const int h = blockIdx.x * 256 + threadIdx.x;
    if (threadIdx.x < S_) aw[threadIdx.x] = attn[b * S_ + threadIdx.x];
    __syncthreads();
    float acc = 0.f;
    for (int s = 0; s < S_; ++s)
        acc += aw[s] * enc[((size_t)s * B_ + b) * H_ + h];
    ctx[b * H_ + h] = acc;
}

// ---------------------------------------------------------------------------
// GRU elementwise: r,u,n gates + h_new
// ---------------------------------------------------------------------------
__global__ void gru_k(const float* __restrict__ gxcz, const float* __restrict__ gh,
                      const float* __restrict__ hlast, float* __restrict__ hnew) {
    const int idx = blockIdx.x * 256 + threadIdx.x;   // 0..65535
    const int b = idx >> 10, h = idx & 1023;
    const float xr = gxcz[b * H3_ + h];
    const float xu = gxcz[b * H3_ + H_ + h];
    const float xn = gxcz[b * H3_ + 2 * H_ + h];
    const float hr = gh[b * H3_ + h];
    const float hu = gh[b * H3_ + H_ + h];
    const float hn = gh[b * H3_ + 2 * H_ + h];
    const float r = 1.f / (1.f + expf(-(xr + hr)));
    const float u = 1.f / (1.f + expf(-(xu + hu)));
    const float n = tanhf(xn + r * hn);
    hnew[idx] = (1.f - u) * n + u * hlast[idx];
}

extern "C" void kernel_launch(void* const* d_in, const int* in_sizes, int n_in,
                              void* d_out, int out_size, void* d_ws, size_t ws_size,
                              hipStream_t stream) {
    const float* emb   = (const float*)d_in[0];
    const float* hid   = (const float*)d_in[1];   // [1,B,H] -> h_last
    const float* enc   = (const float*)d_in[2];   // [S,B,H]
    const float* z     = (const float*)d_in[3];
    const float* Wa    = (const float*)d_in[4];   // [H,2H]
    const float* ba    = (const float*)d_in[5];
    const float* v     = (const float*)d_in[6];
    const float* Wx    = (const float*)d_in[7];   // [3H,E]
    const float* bx    = (const float*)d_in[8];
    const float* Wh    = (const float*)d_in[9];   // [3H,H]
    const float* bh    = (const float*)d_in[10];
    const float* Wc    = (const float*)d_in[11];
    const float* bc    = (const float*)d_in[12];
    const float* Wz    = (const float*)d_in[13];
    const float* bz    = (const float*)d_in[14];
    const float* Wout  = (const float*)d_in[15];  // [V,H]
    const float* bout  = (const float*)d_in[16];

    float* out  = (float*)d_out;                  // [B,V]
    float* hnew = out + (size_t)B_ * V_;          // [B,H]
    float* attn = hnew + (size_t)B_ * H_;         // [B,S]

    float* ws       = (float*)d_ws;
    float* hproj    = ws;                         // 65536
    float* partials = hproj + (size_t)B_ * H_;    // 131072
    float* ctx      = partials + (size_t)B_ * S_ * NT_;  // 65536
    float* gxcz     = ctx + (size_t)B_ * H_;      // 196608
    float* ghbuf    = gxcz + (size_t)B_ * H3_;    // 196608

    const float* hlast = hid;                     // L == 1

    dim3 blk(256);
    // 1. h_proj[b][h] = h_last . Wa1[h,:] + ba[h]
    gemm_nt<<<dim3(H_ / 64, 1), blk, 0, stream>>>(hlast, Wa, ba, hproj, H_, H_, 2 * H_, 0, 0);
    // 2. energy + scores partials
    energy_scores<<<dim3(NT_, S_), blk, 0, stream>>>(enc, Wa, hproj, v, partials);
    // 3. softmax -> attn weights (also an output)
    softmax_attn<<<dim3(B_), dim3(S_), 0, stream>>>(partials, attn);
    // 4. context
    context_k<<<dim3(H_ / 256, B_), blk, 0, stream>>>(attn, enc, ctx);
    // 5-7. gxcz = emb@Wx^T + bx + ctx@Wc^T + bc + z@Wz^T + bz
    gemm_nt<<<dim3(H3_ / 64, 1), blk, 0, stream>>>(emb, Wx, bx, gxcz, H3_, E_, E_, 0, 0);
    gemm_nt<<<dim3(H3_ / 64, 1), blk, 0, stream>>>(ctx, Wc, bc, gxcz, H3_, H_, H_, 0, 1);
    gemm_nt<<<dim3(H3_ / 64, 1), blk, 0, stream>>>(z,   Wz, bz, gxcz, H3_, H_, H_, 0, 1);
    // 8. gh = h_last@Wh^T + bh
    gemm_nt<<<dim3(H3_ / 64, 1), blk, 0, stream>>>(hlast, Wh, bh, ghbuf, H3_, H_, H_, 0, 0);
    // 9. GRU elementwise -> h_new (output)
    gru_k<<<dim3((B_ * H_) / 256), blk, 0, stream>>>(gxcz, ghbuf, hlast, hnew);
    // 10. logits = h_new@Wout^T + bout (output)
    gemm_nt<<<dim3(V_ / 64, 1), blk, 0, stream>>>(hnew, Wout, bout, out, V_, H_, H_, 0, 0);
}

// Round 2
// 418.415 us; speedup vs baseline: 1.4283x; 1.4283x over previous
//
#include <hip/hip_runtime.h>
#include <hip/hip_bf16.h>
#include <math.h>

#define B_  64
#define S_  128
#define E_  512
#define H_  1024
#define V_  32000
#define H3_ 3072
#define NT_ 16

typedef __attribute__((ext_vector_type(8))) short bf16x8;
typedef __attribute__((ext_vector_type(4))) float f32x4;

// ---------------------------------------------------------------------------
// fp32 -> bf16 (round-to-nearest-even)
// ---------------------------------------------------------------------------
__device__ __forceinline__ unsigned short f2b(float f) {
    unsigned int u = __builtin_bit_cast(unsigned int, f);
    u = (u + 0x7fffu + ((u >> 16) & 1u)) >> 16;
    return (unsigned short)u;
}

// cast enc [S*B*H] fp32 -> bf16, 8 elems/thread
__global__ void cast_enc(const float* __restrict__ in, unsigned short* __restrict__ out) {
    const size_t i8 = ((size_t)blockIdx.x * 256 + threadIdx.x) * 8;
    float4 a = *(const float4*)&in[i8];
    float4 b = *(const float4*)&in[i8 + 4];
    unsigned short o[8] = { f2b(a.x), f2b(a.y), f2b(a.z), f2b(a.w),
                            f2b(b.x), f2b(b.y), f2b(b.z), f2b(b.w) };
    *(uint4*)&out[i8] = *(uint4*)o;
}

// cast Wa[:, H:2H] -> Wa2 bf16 [H][H], 8 elems/thread
__global__ void cast_wa2(const float* __restrict__ Wa, unsigned short* __restrict__ out) {
    const int id = blockIdx.x * 256 + threadIdx.x;     // 0..131071
    const int n = id >> 7;                             // row 0..1023
    const int kk = (id & 127) * 8;
    const float* src = &Wa[(size_t)n * (2 * H_) + H_ + kk];
    float4 a = *(const float4*)src;
    float4 b = *(const float4*)(src + 4);
    unsigned short o[8] = { f2b(a.x), f2b(a.y), f2b(a.z), f2b(a.w),
                            f2b(b.x), f2b(b.y), f2b(b.z), f2b(b.w) };
    *(uint4*)&out[(size_t)n * H_ + kk] = *(uint4*)o;
}

// ---------------------------------------------------------------------------
// Generic C[M,N] = (acc ? C : 0) + A[M,K] @ W[N,K]^T (+ bias[N]) ; M == 64
// ---------------------------------------------------------------------------
__global__ void gemm_nt(const float* __restrict__ A, const float* __restrict__ W,
                        const float* __restrict__ bias, float* __restrict__ C,
                        int N, int K, int ldw, int woff, int accumulate) {
    __shared__ float As[16][64];
    __shared__ float Ws[16][64];
    const int n0 = blockIdx.x * 64;
    const int t  = threadIdx.x;
    const int tx = t & 15, ty = t >> 4;
    const int lm = t >> 2;
    const int lk = (t & 3) * 4;

    float c[4][4];
    #pragma unroll
    for (int i = 0; i < 4; ++i)
        #pragma unroll
        for (int j = 0; j < 4; ++j) c[i][j] = 0.f;

    for (int k0 = 0; k0 < K; k0 += 16) {
        float4 av = *(const float4*)&A[lm * K + k0 + lk];
        float4 wv = *(const float4*)&W[(size_t)(n0 + lm) * ldw + woff + k0 + lk];
        As[lk + 0][lm] = av.x; As[lk + 1][lm] = av.y;
        As[lk + 2][lm] = av.z; As[lk + 3][lm] = av.w;
        Ws[lk + 0][lm] = wv.x; Ws[lk + 1][lm] = wv.y;
        Ws[lk + 2][lm] = wv.z; Ws[lk + 3][lm] = wv.w;
        __syncthreads();
        #pragma unroll
        for (int k = 0; k < 16; ++k) {
            float4 a = *(const float4*)&As[k][ty * 4];
            float4 w = *(const float4*)&Ws[k][tx * 4];
            c[0][0] += a.x * w.x; c[0][1] += a.x * w.y; c[0][2] += a.x * w.z; c[0][3] += a.x * w.w;
            c[1][0] += a.y * w.x; c[1][1] += a.y * w.y; c[1][2] += a.y * w.z; c[1][3] += a.y * w.w;
            c[2][0] += a.z * w.x; c[2][1] += a.z * w.y; c[2][2] += a.z * w.z; c[2][3] += a.z * w.w;
            c[3][0] += a.w * w.x; c[3][1] += a.w * w.y; c[3][2] += a.w * w.z; c[3][3] += a.w * w.w;
        }
        __syncthreads();
    }

    #pragma unroll
    for (int i = 0; i < 4; ++i) {
        const int m = ty * 4 + i;
        #pragma unroll
        for (int j = 0; j < 4; ++j) {
            const int n = n0 + tx * 4 + j;
            float val = c[i][j];
            if (bias) val += bias[n];
            if (accumulate) val += C[m * N + n];
            C[m * N + n] = val;
        }
    }
}

// ---------------------------------------------------------------------------
// bf16 MFMA energy+scores: C = enc_b[8192,1024] @ Wa2_b[1024,1024]^T,
// epilogue tanh(C + hproj[b][n]) weighted by v[n], reduced to partials.
// 128x128 tile, 4 waves (2x2), 16x16x32 bf16 MFMA, XOR-swizzled LDS.
// ---------------------------------------------------------------------------
__global__ __launch_bounds__(256) void energy_mfma(
    const unsigned short* __restrict__ Ab, const unsigned short* __restrict__ Bb,
    const float* __restrict__ hproj, const float* __restrict__ v,
    float* __restrict__ partials) {
    __shared__ unsigned short As[128 * 32];   // 8 KB, 16B-slot swizzled
    __shared__ unsigned short Bs[128 * 32];
    const int nb = blockIdx.x;                // 0..7
    const int mb = blockIdx.y;                // 0..63
    const int m0 = mb * 128, n0 = nb * 128;
    const int t = threadIdx.x;
    const int lane = t & 63, w = t >> 6;
    const int wr = w >> 1, wc = w & 1;        // wave position (rows, cols)

    f32x4 acc[4][4];
    #pragma unroll
    for (int i = 0; i < 4; ++i)
        #pragma unroll
        for (int j = 0; j < 4; ++j) acc[i][j] = (f32x4){0.f, 0.f, 0.f, 0.f};

    for (int k0 = 0; k0 < H_; k0 += 32) {
        // stage: 512 16B-chunks per tile; chunk c -> (row=c>>2, slot=c&3)
        #pragma unroll
        for (int r = 0; r < 2; ++r) {
            const int c = r * 256 + t;
            const int row = c >> 2, slot = c & 3;
            const int sw = slot ^ ((row >> 1) & 3);
            uint4 da = *(const uint4*)&Ab[(size_t)(m0 + row) * H_ + k0 + slot * 8];
            *(uint4*)((char*)As + row * 64 + sw * 16) = da;
            uint4 db = *(const uint4*)&Bb[(size_t)(n0 + row) * H_ + k0 + slot * 8];
            *(uint4*)((char*)Bs + row * 64 + sw * 16) = db;
        }
        __syncthreads();
        bf16x8 a[4], b[4];
        #pragma unroll
        for (int i = 0; i < 4; ++i) {
            const int row = wr * 64 + i * 16 + (lane & 15);
            const int sw = (lane >> 4) ^ ((row >> 1) & 3);
            a[i] = *(const bf16x8*)((const char*)As + row * 64 + sw * 16);
        }
        #pragma unroll
        for (int j = 0; j < 4; ++j) {
            const int row = wc * 64 + j * 16 + (lane & 15);
            const int sw = (lane >> 4) ^ ((row >> 1) & 3);
            b[j] = *(const bf16x8*)((const char*)Bs + row * 64 + sw * 16);
        }
        #pragma unroll
        for (int i = 0; i < 4; ++i)
            #pragma unroll
            for (int j = 0; j < 4; ++j)
                acc[i][j] = __builtin_amdgcn_mfma_f32_16x16x32_bf16(a[i], b[j], acc[i][j], 0, 0, 0);
        __syncthreads();
    }

    // epilogue: C/D layout col = lane&15, row = (lane>>4)*4 + q
    float vj[4];
    #pragma unroll
    for (int j = 0; j < 4; ++j) vj[j] = v[n0 + wc * 64 + j * 16 + (lane & 15)];

    const int s = mb * 2 + wr;                // global row m>>6
    #pragma unroll
    for (int i = 0; i < 4; ++i) {
        #pragma unroll
        for (int q = 0; q < 4; ++q) {
            const int b = i * 16 + (lane >> 4) * 4 + q;   // global row m & 63
            float sum = 0.f;
            #pragma unroll
            for (int j = 0; j < 4; ++j) {
                const int n = n0 + wc * 64 + j * 16 + (lane & 15);
                sum += vj[j] * tanhf(acc[i][j][q] + hproj[b * H_ + n]);
            }
            sum += __shfl_xor(sum, 1);
            sum += __shfl_xor(sum, 2);
            sum += __shfl_xor(sum, 4);
            sum += __shfl_xor(sum, 8);
            if ((lane & 15) == 0)
                partials[((size_t)b * S_ + s) * NT_ + nb * 2 + wc] = sum;
        }
    }
}

// ---------------------------------------------------------------------------
// fp32 fallback energy kernel (used only if ws too small for bf16 buffers)
// ---------------------------------------------------------------------------
__global__ void energy_scores(const float* __restrict__ enc, const float* __restrict__ Wa,
                              const float* __restrict__ hproj, const float* __restrict__ v,
                              float* __restrict__ partials) {
    __shared__ float As[16][64];
    __shared__ float Ws[16][64];
    __shared__ float red[64][16];
    const int nt = blockIdx.x;
    const int s  = blockIdx.y;
    const int n0 = nt * 64;
    const float* Arow = enc + (size_t)s * (B_ * H_);
    const int t  = threadIdx.x;
    const int tx = t & 15, ty = t >> 4;
    const int lm = t >> 2;
    const int lk = (t & 3) * 4;

    float c[4][4];
    #pragma unroll
    for (int i = 0; i < 4; ++i)
        #pragma unroll
        for (int j = 0; j < 4; ++j) c[i][j] = 0.f;

    for (int k0 = 0; k0 < H_; k0 += 16) {
        float4 av = *(const float4*)&Arow[lm * H_ + k0 + lk];
        float4 wv = *(const float4*)&Wa[(size_t)(n0 + lm) * (2 * H_) + H_ + k0 + lk];
        As[lk + 0][lm] = av.x; As[lk + 1][lm] = av.y;
        As[lk + 2][lm] = av.z; As[lk + 3][lm] = av.w;
        Ws[lk + 0][lm] = wv.x; Ws[lk + 1][lm] = wv.y;
        Ws[lk + 2][lm] = wv.z; Ws[lk + 3][lm] = wv.w;
        __syncthreads();
        #pragma unroll
        for (int k = 0; k < 16; ++k) {
            float4 a = *(const float4*)&As[k][ty * 4];
            float4 w = *(const float4*)&Ws[k][tx * 4];
            c[0][0] += a.x * w.x; c[0][1] += a.x * w.y; c[0][2] += a.x * w.z; c[0][3] += a.x * w.w;
            c[1][0] += a.y * w.x; c[1][1] += a.y * w.y; c[1][2] += a.y * w.z; c[1][3] += a.y * w.w;
            c[2][0] += a.z * w.x; c[2][1] += a.z * w.y; c[2][2] += a.z * w.z; c[2][3] += a.z * w.w;
            c[3][0] += a.w * w.x; c[3][1] += a.w * w.y; c[3][2] += a.w * w.z; c[3][3] += a.w * w.w;
        }
        __syncthreads();
    }
    #pragma unroll
    for (int i = 0; i < 4; ++i) {
        const int b = ty * 4 + i;
        float part = 0.f;
        #pragma unroll
        for (int j = 0; j < 4; ++j) {
            const int h = n0 + tx * 4 + j;
            part += v[h] * tanhf(c[i][j] + hproj[b * H_ + h]);
        }
        red[b][tx] = part;
    }
    __syncthreads();
    if (t < 64) {
        float sum = 0.f;
        #pragma unroll
        for (int x = 0; x < 16; ++x) sum += red[t][x];
        partials[((size_t)t * S_ + s) * NT_ + nt] = sum;
    }
}

// ---------------------------------------------------------------------------
// softmax over S=128 (reduce 16 partials each)
// ---------------------------------------------------------------------------
__global__ void softmax_attn(const float* __restrict__ partials, float* __restrict__ attn_out) {
    __shared__ float red[128];
    const int b = blockIdx.x;
    const int s = threadIdx.x;
    float sc = 0.f;
    #pragma unroll
    for (int nt = 0; nt < NT_; ++nt) sc += partials[((size_t)b * S_ + s) * NT_ + nt];
    red[s] = sc; __syncthreads();
    for (int o = 64; o > 0; o >>= 1) {
        if (s < o) red[s] = fmaxf(red[s], red[s + o]);
        __syncthreads();
    }
    const float mx = red[0]; __syncthreads();
    const float e = expf(sc - mx);
    red[s] = e; __syncthreads();
    for (int o = 64; o > 0; o >>= 1) {
        if (s < o) red[s] += red[s + o];
        __syncthreads();
    }
    attn_out[b * S_ + s] = e / red[0];
}

__global__ void context_k(const float* __restrict__ attn, const float* __restrict__ enc,
                          float* __restrict__ ctx) {
    __shared__ float aw[S_];
    const int b = blockIdx.y;
    const int h = blockIdx.x * 256 + threadIdx.x;
    if (threadIdx.x < S_) aw[threadIdx.x] = attn[b * S_ + threadIdx.x];
    __syncthreads();
    float acc = 0.f;
    for (int s = 0; s < S_; ++s)
        acc += aw[s] * enc[((size_t)s * B_ + b) * H_ + h];
    ctx[b * H_ + h] = acc;
}

// ---------------------------------------------------------------------------
// Fused gate GEMMs: gxcz = emb@Wx^T + z@Wz^T + ctx@Wc^T + (bx+bz+bc)
//                   gh   = hlast@Wh^T + bh          (N = 3072, M = 64)
// ---------------------------------------------------------------------------
__device__ __forceinline__ void pair_acc(const float* __restrict__ A, const float* __restrict__ W,
                                         int K, int n0, int t, float c[4][4],
                                         float (*As)[64], float (*Ws)[64]) {
    const int tx = t & 15, ty = t >> 4;
    const int lm = t >> 2;
    const int lk = (t & 3) * 4;
    for (int k0 = 0; k0 < K; k0 += 16) {
        float4 av = *(const float4*)&A[lm * K + k0 + lk];
        float4 wv = *(const float4*)&W[(size_t)(n0 + lm) * K + k0 + lk];
        As[lk + 0][lm] = av.x; As[lk + 1][lm] = av.y;
        As[lk + 2][lm] = av.z; As[lk + 3][lm] = av.w;
        Ws[lk + 0][lm] = wv.x; Ws[lk + 1][lm] = wv.y;
        Ws[lk + 2][lm] = wv.z; Ws[lk + 3][lm] = wv.w;
        __syncthreads();
        #pragma unroll
        for (int k = 0; k < 16; ++k) {
            float4 a = *(const float4*)&As[k][ty * 4];
            float4 w = *(const float4*)&Ws[k][tx * 4];
            c[0][0] += a.x * w.x; c[0][1] += a.x * w.y; c[0][2] += a.x * w.z; c[0][3] += a.x * w.w;
            c[1][0] += a.y * w.x; c[1][1] += a.y * w.y; c[1][2] += a.y * w.z; c[1][3] += a.y * w.w;
            c[2][0] += a.z * w.x; c[2][1] += a.z * w.y; c[2][2] += a.z * w.z; c[2][3] += a.z * w.w;
            c[3][0] += a.w * w.x; c[3][1] += a.w * w.y; c[3][2] += a.w * w.z; c[3][3] += a.w * w.w;
        }
        __syncthreads();
    }
}

__global__ void gates_k(const float* __restrict__ emb, const float* __restrict__ z,
                        const float* __restrict__ ctx, const float* __restrict__ hlast,
                        const float* __restrict__ Wx, const float* __restrict__ Wz,
                        const float* __restrict__ Wc, const float* __restrict__ Wh,
                        const float* __restrict__ bx, const float* __restrict__ bz,
                        const float* __restrict__ bc, const float* __restrict__ bh,
                        float* __restrict__ gxcz, float* __restrict__ gh) {
    __shared__ float As[16][64];
    __shared__ float Ws[16][64];
    const int n0 = blockIdx.x * 64;
    const int t  = threadIdx.x;
    const int tx = t & 15, ty = t >> 4;

    float c0[4][4], c1[4][4];
    #pragma unroll
    for (int i = 0; i < 4; ++i)
        #pragma unroll
        for (int j = 0; j < 4; ++j) { c0[i][j] = 0.f; c1[i][j] = 0.f; }

    pair_acc(emb,   Wx, E_, n0, t, c0, As, Ws);
    pair_acc(z,     Wz, H_, n0, t, c0, As, Ws);
    pair_acc(ctx,   Wc, H_, n0, t, c0, As, Ws);
    pair_acc(hlast, Wh, H_, n0, t, c1, As, Ws);

    #pragma unroll
    for (int i = 0; i < 4; ++i) {
        const int m = ty * 4 + i;
        #pragma unroll
        for (int j = 0; j < 4; ++j) {
            const int n = n0 + tx * 4 + j;
            gxcz[m * H3_ + n] = c0[i][j] + bx[n] + bz[n] + bc[n];
            gh[m * H3_ + n]   = c1[i][j] + bh[n];
        }
    }
}

__global__ void gru_k(const float* __restrict__ gxcz, const float* __restrict__ gh,
                      const float* __restrict__ hlast, float* __restrict__ hnew) {
    const int idx = blockIdx.x * 256 + threadIdx.x;
    const int b = idx >> 10, h = idx & 1023;
    const float xr = gxcz[b * H3_ + h];
    const float xu = gxcz[b * H3_ + H_ + h];
    const float xn = gxcz[b * H3_ + 2 * H_ + h];
    const float hr = gh[b * H3_ + h];
    const float hu = gh[b * H3_ + H_ + h];
    const float hn = gh[b * H3_ + 2 * H_ + h];
    const float r = 1.f / (1.f + expf(-(xr + hr)));
    const float u = 1.f / (1.f + expf(-(xu + hu)));
    const float n = tanhf(xn + r * hn);
    hnew[idx] = (1.f - u) * n + u * hlast[idx];
}

extern "C" void kernel_launch(void* const* d_in, const int* in_sizes, int n_in,
                              void* d_out, int out_size, void* d_ws, size_t ws_size,
                              hipStream_t stream) {
    const float* emb   = (const float*)d_in[0];
    const float* hid   = (const float*)d_in[1];
    const float* enc   = (const float*)d_in[2];
    const float* z     = (const float*)d_in[3];
    const float* Wa    = (const float*)d_in[4];
    const float* ba    = (const float*)d_in[5];
    const float* v     = (const float*)d_in[6];
    const float* Wx    = (const float*)d_in[7];
    const float* bx    = (const float*)d_in[8];
    const float* Wh    = (const float*)d_in[9];
    const float* bh    = (const float*)d_in[10];
    const float* Wc    = (const float*)d_in[11];
    const float* bc    = (const float*)d_in[12];
    const float* Wz    = (const float*)d_in[13];
    const float* bz    = (const float*)d_in[14];
    const float* Wout  = (const float*)d_in[15];
    const float* bout  = (const float*)d_in[16];

    float* out  = (float*)d_out;
    float* hnew = out + (size_t)B_ * V_;
    float* attn = hnew + (size_t)B_ * H_;

    float* ws       = (float*)d_ws;
    float* hproj    = ws;
    float* partials = hproj + (size_t)B_ * H_;
    float* ctx      = partials + (size_t)B_ * S_ * NT_;
    float* gxcz     = ctx + (size_t)B_ * H_;
    float* ghbuf    = gxcz + (size_t)B_ * H3_;
    float* f32_end  = ghbuf + (size_t)B_ * H3_;

    unsigned short* encb = (unsigned short*)f32_end;                  // 16.8 MB
    unsigned short* wa2b = encb + (size_t)S_ * B_ * H_;               // 2.1 MB
    const size_t need = (size_t)((char*)(wa2b + (size_t)H_ * H_) - (char*)d_ws);

    const float* hlast = hid;
    dim3 blk(256);

    // 1. h_proj = h_last @ Wa1^T + ba
    gemm_nt<<<dim3(H_ / 64, 1), blk, 0, stream>>>(hlast, Wa, ba, hproj, H_, H_, 2 * H_, 0, 0);

    if (ws_size >= need) {
        // 2. casts + bf16 MFMA energy/scores
        cast_enc<<<dim3((S_ * B_ * H_) / (256 * 8)), blk, 0, stream>>>(enc, encb);
        cast_wa2<<<dim3((H_ * H_) / (256 * 8)), blk, 0, stream>>>(Wa, wa2b);
        energy_mfma<<<dim3(H_ / 128, (S_ * B_) / 128), blk, 0, stream>>>(encb, wa2b, hproj, v, partials);
    } else {
        energy_scores<<<dim3(NT_, S_), blk, 0, stream>>>(enc, Wa, hproj, v, partials);
    }

    // 3. softmax (writes attn output)
    softmax_attn<<<dim3(B_), dim3(S_), 0, stream>>>(partials, attn);
    // 4. context
    context_k<<<dim3(H_ / 256, B_), blk, 0, stream>>>(attn, enc, ctx);
    // 5. fused gate GEMMs
    gates_k<<<dim3(H3_ / 64, 1), blk, 0, stream>>>(emb, z, ctx, hlast,
                                                   Wx, Wz, Wc, Wh,
                                                   bx, bz, bc, bh, gxcz, ghbuf);
    // 6. GRU elementwise (writes hnew output)
    gru_k<<<dim3((B_ * H_) / 256), blk, 0, stream>>>(gxcz, ghbuf, hlast, hnew);
    // 7. logits (writes main output)
    gemm_nt<<<dim3(V_ / 64, 1), blk, 0, stream>>>(hnew, Wout, bout, out, V_, H_, H_, 0, 0);
}

// Round 3
// 192.937 us; speedup vs baseline: 3.0974x; 2.1687x over previous
//
#include <hip/hip_runtime.h>
#include <hip/hip_bf16.h>
#include <math.h>

#define B_  64
#define S_  128
#define E_  512
#define H_  1024
#define V_  32000
#define H3_ 3072
#define NT_ 16

typedef __attribute__((ext_vector_type(8))) short bf16x8;
typedef __attribute__((ext_vector_type(4))) float f32x4;

__device__ __forceinline__ unsigned short f2b(float f) {
    unsigned int u = __builtin_bit_cast(unsigned int, f);
    u = (u + 0x7fffu + ((u >> 16) & 1u)) >> 16;
    return (unsigned short)u;
}

// cast enc [S*B*H] fp32 -> bf16, 8 elems/thread
__global__ void cast_enc(const float* __restrict__ in, unsigned short* __restrict__ out) {
    const size_t i8 = ((size_t)blockIdx.x * 256 + threadIdx.x) * 8;
    float4 a = *(const float4*)&in[i8];
    float4 b = *(const float4*)&in[i8 + 4];
    unsigned short o[8] = { f2b(a.x), f2b(a.y), f2b(a.z), f2b(a.w),
                            f2b(b.x), f2b(b.y), f2b(b.z), f2b(b.w) };
    *(uint4*)&out[i8] = *(uint4*)o;
}

// cast Wa[:, H:2H] -> bf16 [H][H]
__global__ void cast_wa2(const float* __restrict__ Wa, unsigned short* __restrict__ out) {
    const int id = blockIdx.x * 256 + threadIdx.x;
    const int n = id >> 7;
    const int kk = (id & 127) * 8;
    const float* src = &Wa[(size_t)n * (2 * H_) + H_ + kk];
    float4 a = *(const float4*)src;
    float4 b = *(const float4*)(src + 4);
    unsigned short o[8] = { f2b(a.x), f2b(a.y), f2b(a.z), f2b(a.w),
                            f2b(b.x), f2b(b.y), f2b(b.z), f2b(b.w) };
    *(uint4*)&out[(size_t)n * H_ + kk] = *(uint4*)o;
}

// ---------------------------------------------------------------------------
// fp32 64x64-tile inner product over a K span (shared by splitk kernels)
// ---------------------------------------------------------------------------
__device__ __forceinline__ void tile_acc(const float* __restrict__ A, int lda,
                                         const float* __restrict__ Wrow0, int ldw,
                                         int kspan, int t, float c[4][4],
                                         float (*As)[64], float (*Ws)[64]) {
    const int tx = t & 15, ty = t >> 4;
    const int lm = t >> 2;
    const int lk = (t & 3) * 4;
    for (int k0 = 0; k0 < kspan; k0 += 16) {
        float4 av = *(const float4*)&A[lm * lda + k0 + lk];
        float4 wv = *(const float4*)&Wrow0[(size_t)lm * ldw + k0 + lk];
        As[lk + 0][lm] = av.x; As[lk + 1][lm] = av.y;
        As[lk + 2][lm] = av.z; As[lk + 3][lm] = av.w;
        Ws[lk + 0][lm] = wv.x; Ws[lk + 1][lm] = wv.y;
        Ws[lk + 2][lm] = wv.z; Ws[lk + 3][lm] = wv.w;
        __syncthreads();
        #pragma unroll
        for (int k = 0; k < 16; ++k) {
            float4 a = *(const float4*)&As[k][ty * 4];
            float4 w = *(const float4*)&Ws[k][tx * 4];
            c[0][0] += a.x * w.x; c[0][1] += a.x * w.y; c[0][2] += a.x * w.z; c[0][3] += a.x * w.w;
            c[1][0] += a.y * w.x; c[1][1] += a.y * w.y; c[1][2] += a.y * w.z; c[1][3] += a.y * w.w;
            c[2][0] += a.z * w.x; c[2][1] += a.z * w.y; c[2][2] += a.z * w.z; c[2][3] += a.z * w.w;
            c[3][0] += a.w * w.x; c[3][1] += a.w * w.y; c[3][2] += a.w * w.z; c[3][3] += a.w * w.w;
        }
        __syncthreads();
    }
}

// ---------------------------------------------------------------------------
// Wout GEMM (N=32000, K=1024, M=64): enough blocks already, keep direct form
// ---------------------------------------------------------------------------
__global__ void gemm_nt(const float* __restrict__ A, const float* __restrict__ W,
                        const float* __restrict__ bias, float* __restrict__ C,
                        int N, int K) {
    __shared__ float As[16][64];
    __shared__ float Ws[16][64];
    const int n0 = blockIdx.x * 64;
    const int t  = threadIdx.x;
    const int tx = t & 15, ty = t >> 4;

    float c[4][4];
    #pragma unroll
    for (int i = 0; i < 4; ++i)
        #pragma unroll
        for (int j = 0; j < 4; ++j) c[i][j] = 0.f;

    tile_acc(A, K, &W[(size_t)n0 * K], K, K, t, c, As, Ws);

    #pragma unroll
    for (int i = 0; i < 4; ++i) {
        const int m = ty * 4 + i;
        #pragma unroll
        for (int j = 0; j < 4; ++j) {
            const int n = n0 + tx * 4 + j;
            C[m * N + n] = c[i][j] + bias[n];
        }
    }
}

// ---------------------------------------------------------------------------
// hproj split-K: grid (16 ntiles, 8 kchunks of 128); hpp[c][64][1024]
// ---------------------------------------------------------------------------
__global__ void hproj_splitk(const float* __restrict__ h, const float* __restrict__ Wa,
                             float* __restrict__ hpp) {
    __shared__ float As[16][64];
    __shared__ float Ws[16][64];
    const int n0 = blockIdx.x * 64;
    const int kb = blockIdx.y * 128;
    const int t  = threadIdx.x;
    const int tx = t & 15, ty = t >> 4;

    float c[4][4];
    #pragma unroll
    for (int i = 0; i < 4; ++i)
        #pragma unroll
        for (int j = 0; j < 4; ++j) c[i][j] = 0.f;

    tile_acc(&h[kb], H_, &Wa[(size_t)n0 * (2 * H_) + kb], 2 * H_, 128, t, c, As, Ws);

    float* dst = hpp + (size_t)blockIdx.y * B_ * H_;
    #pragma unroll
    for (int i = 0; i < 4; ++i) {
        const int m = ty * 4 + i;
        #pragma unroll
        for (int j = 0; j < 4; ++j)
            dst[m * H_ + n0 + tx * 4 + j] = c[i][j];
    }
}

__global__ void reduce_hproj(const float* __restrict__ hpp, const float* __restrict__ ba,
                             float* __restrict__ hproj) {
    const int idx = blockIdx.x * 256 + threadIdx.x;   // 0..65535
    const int hh = idx & 1023;
    float s = ba[hh];
    #pragma unroll
    for (int c = 0; c < 8; ++c) s += hpp[(size_t)c * B_ * H_ + idx];
    hproj[idx] = s;
}

// ---------------------------------------------------------------------------
// Gate GEMMs split-K: grid (48 ntiles, 7 chunks of 512) -> P[7][64][3072]
// yc 0: emb@Wx ; 1,2: z@Wz ; 3,4: ctx@Wc ; 5,6: h@Wh
// ---------------------------------------------------------------------------
__global__ void gates_splitk(const float* __restrict__ emb, const float* __restrict__ z,
                             const float* __restrict__ ctx, const float* __restrict__ h,
                             const float* __restrict__ Wx, const float* __restrict__ Wz,
                             const float* __restrict__ Wc, const float* __restrict__ Wh,
                             float* __restrict__ P) {
    __shared__ float As[16][64];
    __shared__ float Ws[16][64];
    const int n0 = blockIdx.x * 64;
    const int yc = blockIdx.y;
    const int t  = threadIdx.x;
    const int tx = t & 15, ty = t >> 4;

    const float* A; const float* W; int lda, kb;
    if (yc == 0)      { A = emb; W = Wx; lda = E_; kb = 0; }
    else if (yc <= 2) { A = z;   W = Wz; lda = H_; kb = (yc - 1) * 512; }
    else if (yc <= 4) { A = ctx; W = Wc; lda = H_; kb = (yc - 3) * 512; }
    else              { A = h;   W = Wh; lda = H_; kb = (yc - 5) * 512; }

    float c[4][4];
    #pragma unroll
    for (int i = 0; i < 4; ++i)
        #pragma unroll
        for (int j = 0; j < 4; ++j) c[i][j] = 0.f;

    tile_acc(&A[kb], lda, &W[(size_t)n0 * lda + kb], lda, 512, t, c, As, Ws);

    float* dst = P + (size_t)yc * B_ * H3_;
    #pragma unroll
    for (int i = 0; i < 4; ++i) {
        const int m = ty * 4 + i;
        #pragma unroll
        for (int j = 0; j < 4; ++j)
            dst[m * H3_ + n0 + tx * 4 + j] = c[i][j];
    }
}

// ---------------------------------------------------------------------------
// bf16 MFMA energy+scores (128x128 tile, 4 waves, 16x16x32, swizzled LDS)
// ---------------------------------------------------------------------------
__global__ __launch_bounds__(256) void energy_mfma(
    const unsigned short* __restrict__ Ab, const unsigned short* __restrict__ Bb,
    const float* __restrict__ hproj, const float* __restrict__ v,
    float* __restrict__ partials) {
    __shared__ unsigned short As[128 * 32];
    __shared__ unsigned short Bs[128 * 32];
    const int nb = blockIdx.x;
    const int mb = blockIdx.y;
    const int m0 = mb * 128, n0 = nb * 128;
    const int t = threadIdx.x;
    const int lane = t & 63, w = t >> 6;
    const int wr = w >> 1, wc = w & 1;

    f32x4 acc[4][4];
    #pragma unroll
    for (int i = 0; i < 4; ++i)
        #pragma unroll
        for (int j = 0; j < 4; ++j) acc[i][j] = (f32x4){0.f, 0.f, 0.f, 0.f};

    for (int k0 = 0; k0 < H_; k0 += 32) {
        #pragma unroll
        for (int r = 0; r < 2; ++r) {
            const int c = r * 256 + t;
            const int row = c >> 2, slot = c & 3;
            const int sw = slot ^ ((row >> 1) & 3);
            uint4 da = *(const uint4*)&Ab[(size_t)(m0 + row) * H_ + k0 + slot * 8];
            *(uint4*)((char*)As + row * 64 + sw * 16) = da;
            uint4 db = *(const uint4*)&Bb[(size_t)(n0 + row) * H_ + k0 + slot * 8];
            *(uint4*)((char*)Bs + row * 64 + sw * 16) = db;
        }
        __syncthreads();
        bf16x8 a[4], b[4];
        #pragma unroll
        for (int i = 0; i < 4; ++i) {
            const int row = wr * 64 + i * 16 + (lane & 15);
            const int sw = (lane >> 4) ^ ((row >> 1) & 3);
            a[i] = *(const bf16x8*)((const char*)As + row * 64 + sw * 16);
        }
        #pragma unroll
        for (int j = 0; j < 4; ++j) {
            const int row = wc * 64 + j * 16 + (lane & 15);
            const int sw = (lane >> 4) ^ ((row >> 1) & 3);
            b[j] = *(const bf16x8*)((const char*)Bs + row * 64 + sw * 16);
        }
        #pragma unroll
        for (int i = 0; i < 4; ++i)
            #pragma unroll
            for (int j = 0; j < 4; ++j)
                acc[i][j] = __builtin_amdgcn_mfma_f32_16x16x32_bf16(a[i], b[j], acc[i][j], 0, 0, 0);
        __syncthreads();
    }

    float vj[4];
    #pragma unroll
    for (int j = 0; j < 4; ++j) vj[j] = v[n0 + wc * 64 + j * 16 + (lane & 15)];

    const int s = mb * 2 + wr;
    #pragma unroll
    for (int i = 0; i < 4; ++i) {
        #pragma unroll
        for (int q = 0; q < 4; ++q) {
            const int b = i * 16 + (lane >> 4) * 4 + q;
            float sum = 0.f;
            #pragma unroll
            for (int j = 0; j < 4; ++j) {
                const int n = n0 + wc * 64 + j * 16 + (lane & 15);
                sum += vj[j] * tanhf(acc[i][j][q] + hproj[b * H_ + n]);
            }
            sum += __shfl_xor(sum, 1);
            sum += __shfl_xor(sum, 2);
            sum += __shfl_xor(sum, 4);
            sum += __shfl_xor(sum, 8);
            if ((lane & 15) == 0)
                partials[((size_t)b * S_ + s) * NT_ + nb * 2 + wc] = sum;
        }
    }
}

// fp32 fallback (only if ws too small)
__global__ void energy_scores(const float* __restrict__ enc, const float* __restrict__ Wa,
                              const float* __restrict__ hproj, const float* __restrict__ v,
                              float* __restrict__ partials) {
    __shared__ float As[16][64];
    __shared__ float Ws[16][64];
    __shared__ float red[64][16];
    const int nt = blockIdx.x;
    const int s  = blockIdx.y;
    const int n0 = nt * 64;
    const float* Arow = enc + (size_t)s * (B_ * H_);
    const int t  = threadIdx.x;
    const int tx = t & 15, ty = t >> 4;

    float c[4][4];
    #pragma unroll
    for (int i = 0; i < 4; ++i)
        #pragma unroll
        for (int j = 0; j < 4; ++j) c[i][j] = 0.f;

    tile_acc(Arow, H_, &Wa[(size_t)n0 * (2 * H_) + H_], 2 * H_, H_, t, c, As, Ws);

    #pragma unroll
    for (int i = 0; i < 4; ++i) {
        const int b = ty * 4 + i;
        float part = 0.f;
        #pragma unroll
        for (int j = 0; j < 4; ++j) {
            const int h = n0 + tx * 4 + j;
            part += v[h] * tanhf(c[i][j] + hproj[b * H_ + h]);
        }
        red[b][tx] = part;
    }
    __syncthreads();
    if (t < 64) {
        float sum = 0.f;
        #pragma unroll
        for (int x = 0; x < 16; ++x) sum += red[t][x];
        partials[((size_t)t * S_ + s) * NT_ + nt] = sum;
    }
}

__global__ void softmax_attn(const float* __restrict__ partials, float* __restrict__ attn_out) {
    __shared__ float red[128];
    const int b = blockIdx.x;
    const int s = threadIdx.x;
    float sc = 0.f;
    #pragma unroll
    for (int nt = 0; nt < NT_; ++nt) sc += partials[((size_t)b * S_ + s) * NT_ + nt];
    red[s] = sc; __syncthreads();
    for (int o = 64; o > 0; o >>= 1) {
        if (s < o) red[s] = fmaxf(red[s], red[s + o]);
        __syncthreads();
    }
    const float mx = red[0]; __syncthreads();
    const float e = expf(sc - mx);
    red[s] = e; __syncthreads();
    for (int o = 64; o > 0; o >>= 1) {
        if (s < o) red[s] += red[s + o];
        __syncthreads();
    }
    attn_out[b * S_ + s] = e / red[0];
}

__global__ void context_k(const float* __restrict__ attn, const float* __restrict__ enc,
                          float* __restrict__ ctx) {
    __shared__ float aw[S_];
    const int b = blockIdx.y;
    const int h = blockIdx.x * 256 + threadIdx.x;
    if (threadIdx.x < S_) aw[threadIdx.x] = attn[b * S_ + threadIdx.x];
    __syncthreads();
    float acc = 0.f;
    for (int s = 0; s < S_; ++s)
        acc += aw[s] * enc[((size_t)s * B_ + b) * H_ + h];
    ctx[b * H_ + h] = acc;
}

// ---------------------------------------------------------------------------
// GRU elementwise incl. 7-way partial reduce + biases
// ---------------------------------------------------------------------------
__global__ void gru_k(const float* __restrict__ P, const float* __restrict__ hlast,
                      const float* __restrict__ bx, const float* __restrict__ bz,
                      const float* __restrict__ bc, const float* __restrict__ bh,
                      float* __restrict__ hnew) {
    const int idx = blockIdx.x * 256 + threadIdx.x;
    const int b = idx >> 10, h = idx & 1023;
    float x[3], hg[3];
    #pragma unroll
    for (int g = 0; g < 3; ++g) {
        const int col = g * H_ + h;
        float sx = bx[col] + bz[col] + bc[col];
        #pragma unroll
        for (int c = 0; c < 5; ++c) sx += P[((size_t)c * B_ + b) * H3_ + col];
        float sh = bh[col];
        #pragma unroll
        for (int c = 5; c < 7; ++c) sh += P[((size_t)c * B_ + b) * H3_ + col];
        x[g] = sx; hg[g] = sh;
    }
    const float r = 1.f / (1.f + expf(-(x[0] + hg[0])));
    const float u = 1.f / (1.f + expf(-(x[1] + hg[1])));
    const float n = tanhf(x[2] + r * hg[2]);
    hnew[idx] = (1.f - u) * n + u * hlast[idx];
}

extern "C" void kernel_launch(void* const* d_in, const int* in_sizes, int n_in,
                              void* d_out, int out_size, void* d_ws, size_t ws_size,
                              hipStream_t stream) {
    const float* emb   = (const float*)d_in[0];
    const float* hid   = (const float*)d_in[1];
    const float* enc   = (const float*)d_in[2];
    const float* z     = (const float*)d_in[3];
    const float* Wa    = (const float*)d_in[4];
    const float* ba    = (const float*)d_in[5];
    const float* v     = (const float*)d_in[6];
    const float* Wx    = (const float*)d_in[7];
    const float* bx    = (const float*)d_in[8];
    const float* Wh    = (const float*)d_in[9];
    const float* bh    = (const float*)d_in[10];
    const float* Wc    = (const float*)d_in[11];
    const float* bc    = (const float*)d_in[12];
    const float* Wz    = (const float*)d_in[13];
    const float* bz    = (const float*)d_in[14];
    const float* Wout  = (const float*)d_in[15];
    const float* bout  = (const float*)d_in[16];

    float* out  = (float*)d_out;
    float* hnew = out + (size_t)B_ * V_;
    float* attn = hnew + (size_t)B_ * H_;

    // ws layout: [hproj 64K][spart 128K][ctx 64K][union: encb+wa2b bf16 | hpp | P]
    float* hproj = (float*)d_ws;
    float* spart = hproj + (size_t)B_ * H_;
    float* ctx   = spart + (size_t)B_ * S_ * NT_;
    float* uni   = ctx + (size_t)B_ * H_;
    unsigned short* encb = (unsigned short*)uni;                 // 8.39M shorts
    unsigned short* wa2b = encb + (size_t)S_ * B_ * H_;          // 1.05M shorts
    float* hpp = uni;                                            // 8*64K floats (pre-cast)
    float* P   = uni;                                            // 7*192K floats (post-energy)
    const size_t need = (size_t)((char*)(wa2b + (size_t)H_ * H_) - (char*)d_ws);

    const float* hlast = hid;
    dim3 blk(256);

    // 1. hproj = h @ Wa1^T + ba (split-K, 128 blocks)
    hproj_splitk<<<dim3(H_ / 64, 8), blk, 0, stream>>>(hlast, Wa, hpp);
    reduce_hproj<<<dim3((B_ * H_) / 256), blk, 0, stream>>>(hpp, ba, hproj);

    if (ws_size >= need) {
        cast_enc<<<dim3((S_ * B_ * H_) / (256 * 8)), blk, 0, stream>>>(enc, encb);
        cast_wa2<<<dim3((H_ * H_) / (256 * 8)), blk, 0, stream>>>(Wa, wa2b);
        energy_mfma<<<dim3(H_ / 128, (S_ * B_) / 128), blk, 0, stream>>>(encb, wa2b, hproj, v, spart);
    } else {
        energy_scores<<<dim3(NT_, S_), blk, 0, stream>>>(enc, Wa, hproj, v, spart);
    }

    softmax_attn<<<dim3(B_), dim3(S_), 0, stream>>>(spart, attn);
    context_k<<<dim3(H_ / 256, B_), blk, 0, stream>>>(attn, enc, ctx);

    // gates: split-K over 7 chunks (P aliases encb region — energy is done)
    gates_splitk<<<dim3(H3_ / 64, 7), blk, 0, stream>>>(emb, z, ctx, hlast,
                                                        Wx, Wz, Wc, Wh, P);
    gru_k<<<dim3((B_ * H_) / 256), blk, 0, stream>>>(P, hlast, bx, bz, bc, bh, hnew);

    // logits
    gemm_nt<<<dim3(V_ / 64, 1), blk, 0, stream>>>(hnew, Wout, bout, out, V_, H_);
}

// Round 4
// 147.557 us; speedup vs baseline: 4.0500x; 1.3075x over previous
//
#include <hip/hip_runtime.h>
#include <hip/hip_bf16.h>
#include <math.h>

#define B_  64
#define S_  128
#define E_  512
#define H_  1024
#define V_  32000
#define H3_ 3072
#define NT_ 16

typedef __attribute__((ext_vector_type(8))) short bf16x8;
typedef __attribute__((ext_vector_type(4))) float f32x4;

__device__ __forceinline__ unsigned short f2b(float f) {
    unsigned int u = __builtin_bit_cast(unsigned int, f);
    u = (u + 0x7fffu + ((u >> 16) & 1u)) >> 16;
    return (unsigned short)u;
}

// generic fp32 -> bf16 cast, 8 elems/thread (n8 = total/8 blocks of 256)
__global__ void cast_bf16(const float* __restrict__ in, unsigned short* __restrict__ out) {
    const size_t i8 = ((size_t)blockIdx.x * 256 + threadIdx.x) * 8;
    float4 a = *(const float4*)&in[i8];
    float4 b = *(const float4*)&in[i8 + 4];
    unsigned short o[8] = { f2b(a.x), f2b(a.y), f2b(a.z), f2b(a.w),
                            f2b(b.x), f2b(b.y), f2b(b.z), f2b(b.w) };
    *(uint4*)&out[i8] = *(uint4*)o;
}

// cast Wa[:, H:2H] -> bf16 [H][H]
__global__ void cast_wa2(const float* __restrict__ Wa, unsigned short* __restrict__ out) {
    const int id = blockIdx.x * 256 + threadIdx.x;
    const int n = id >> 7;
    const int kk = (id & 127) * 8;
    const float* src = &Wa[(size_t)n * (2 * H_) + H_ + kk];
    float4 a = *(const float4*)src;
    float4 b = *(const float4*)(src + 4);
    unsigned short o[8] = { f2b(a.x), f2b(a.y), f2b(a.z), f2b(a.w),
                            f2b(b.x), f2b(b.y), f2b(b.z), f2b(b.w) };
    *(uint4*)&out[(size_t)n * H_ + kk] = *(uint4*)o;
}

// ---------------------------------------------------------------------------
// fp32 64x64-tile inner product over a K span (shared by splitk kernels)
// ---------------------------------------------------------------------------
__device__ __forceinline__ void tile_acc(const float* __restrict__ A, int lda,
                                         const float* __restrict__ Wrow0, int ldw,
                                         int kspan, int t, float c[4][4],
                                         float (*As)[64], float (*Ws)[64]) {
    const int tx = t & 15, ty = t >> 4;
    const int lm = t >> 2;
    const int lk = (t & 3) * 4;
    for (int k0 = 0; k0 < kspan; k0 += 16) {
        float4 av = *(const float4*)&A[lm * lda + k0 + lk];
        float4 wv = *(const float4*)&Wrow0[(size_t)lm * ldw + k0 + lk];
        As[lk + 0][lm] = av.x; As[lk + 1][lm] = av.y;
        As[lk + 2][lm] = av.z; As[lk + 3][lm] = av.w;
        Ws[lk + 0][lm] = wv.x; Ws[lk + 1][lm] = wv.y;
        Ws[lk + 2][lm] = wv.z; Ws[lk + 3][lm] = wv.w;
        __syncthreads();
        #pragma unroll
        for (int k = 0; k < 16; ++k) {
            float4 a = *(const float4*)&As[k][ty * 4];
            float4 w = *(const float4*)&Ws[k][tx * 4];
            c[0][0] += a.x * w.x; c[0][1] += a.x * w.y; c[0][2] += a.x * w.z; c[0][3] += a.x * w.w;
            c[1][0] += a.y * w.x; c[1][1] += a.y * w.y; c[1][2] += a.y * w.z; c[1][3] += a.y * w.w;
            c[2][0] += a.z * w.x; c[2][1] += a.z * w.y; c[2][2] += a.z * w.z; c[2][3] += a.z * w.w;
            c[3][0] += a.w * w.x; c[3][1] += a.w * w.y; c[3][2] += a.w * w.z; c[3][3] += a.w * w.w;
        }
        __syncthreads();
    }
}

// fp32 fallback Wout GEMM (used only if ws too small)
__global__ void gemm_nt(const float* __restrict__ A, const float* __restrict__ W,
                        const float* __restrict__ bias, float* __restrict__ C,
                        int N, int K) {
    __shared__ float As[16][64];
    __shared__ float Ws[16][64];
    const int n0 = blockIdx.x * 64;
    const int t  = threadIdx.x;
    const int tx = t & 15, ty = t >> 4;
    float c[4][4];
    #pragma unroll
    for (int i = 0; i < 4; ++i)
        #pragma unroll
        for (int j = 0; j < 4; ++j) c[i][j] = 0.f;
    tile_acc(A, K, &W[(size_t)n0 * K], K, K, t, c, As, Ws);
    #pragma unroll
    for (int i = 0; i < 4; ++i) {
        const int m = ty * 4 + i;
        #pragma unroll
        for (int j = 0; j < 4; ++j) {
            const int n = n0 + tx * 4 + j;
            C[m * N + n] = c[i][j] + bias[n];
        }
    }
}

// ---------------------------------------------------------------------------
// Wout bf16-MFMA GEMM with in-kernel W fp32->bf16 conversion during staging.
// C[64, 32000] = Ab[64,1024](bf16) @ W[32000,1024](fp32, cast on the fly)^T + bias
// Tile 64x64, BK=64, 4 waves (2x2), 16x16x32 MFMA, XOR-swizzled LDS.
// ---------------------------------------------------------------------------
__global__ __launch_bounds__(256) void wout_mfma(
    const unsigned short* __restrict__ Ab, const float* __restrict__ W,
    const float* __restrict__ bias, float* __restrict__ C) {
    __shared__ unsigned short As[64 * 64];   // 8 KB, rows of 128 B, swizzled
    __shared__ unsigned short Bs[64 * 64];
    const int n0 = blockIdx.x * 64;
    const int t = threadIdx.x;
    const int lane = t & 63, w = t >> 6;
    const int wr = w >> 1, wc = w & 1;

    f32x4 acc[2][2];
    #pragma unroll
    for (int i = 0; i < 2; ++i)
        #pragma unroll
        for (int j = 0; j < 2; ++j) acc[i][j] = (f32x4){0.f, 0.f, 0.f, 0.f};

    for (int k0 = 0; k0 < H_; k0 += 64) {
        // stage A (already bf16): 512 16B slots
        #pragma unroll
        for (int r = 0; r < 2; ++r) {
            const int c = r * 256 + t;
            const int row = c >> 3, slot = c & 7;
            const int sw = slot ^ (row & 7);
            uint4 da = *(const uint4*)&Ab[(size_t)row * H_ + k0 + slot * 8];
            *(uint4*)((char*)As + row * 128 + sw * 16) = da;
        }
        // stage B with conversion: 64 rows x 64 k fp32 = 1024 float4
        #pragma unroll
        for (int r = 0; r < 4; ++r) {
            const int c = r * 256 + t;
            const int row = c >> 4, q4 = c & 15;
            const float4 wv = *(const float4*)&W[(size_t)(n0 + row) * H_ + k0 + q4 * 4];
            uint2 pk;
            pk.x = (unsigned int)f2b(wv.x) | ((unsigned int)f2b(wv.y) << 16);
            pk.y = (unsigned int)f2b(wv.z) | ((unsigned int)f2b(wv.w) << 16);
            const int slot = q4 >> 1, half = q4 & 1;
            const int sw = slot ^ (row & 7);
            *(uint2*)((char*)Bs + row * 128 + sw * 16 + half * 8) = pk;
        }
        __syncthreads();
        #pragma unroll
        for (int kk = 0; kk < 2; ++kk) {
            bf16x8 a[2], b[2];
            #pragma unroll
            for (int i = 0; i < 2; ++i) {
                const int row = wr * 32 + i * 16 + (lane & 15);
                const int sw = (kk * 4 + (lane >> 4)) ^ (row & 7);
                a[i] = *(const bf16x8*)((const char*)As + row * 128 + sw * 16);
            }
            #pragma unroll
            for (int j = 0; j < 2; ++j) {
                const int row = wc * 32 + j * 16 + (lane & 15);
                const int sw = (kk * 4 + (lane >> 4)) ^ (row & 7);
                b[j] = *(const bf16x8*)((const char*)Bs + row * 128 + sw * 16);
            }
            #pragma unroll
            for (int i = 0; i < 2; ++i)
                #pragma unroll
                for (int j = 0; j < 2; ++j)
                    acc[i][j] = __builtin_amdgcn_mfma_f32_16x16x32_bf16(a[i], b[j], acc[i][j], 0, 0, 0);
        }
        __syncthreads();
    }

    #pragma unroll
    for (int i = 0; i < 2; ++i)
        #pragma unroll
        for (int j = 0; j < 2; ++j) {
            const int n = n0 + wc * 32 + j * 16 + (lane & 15);
            const float bn = bias[n];
            #pragma unroll
            for (int q = 0; q < 4; ++q) {
                const int m = wr * 32 + i * 16 + (lane >> 4) * 4 + q;
                C[(size_t)m * V_ + n] = acc[i][j][q] + bn;
            }
        }
}

// ---------------------------------------------------------------------------
// hproj split-K: grid (16 ntiles, 8 kchunks of 128); hpp[c][64][1024]
// ---------------------------------------------------------------------------
__global__ void hproj_splitk(const float* __restrict__ h, const float* __restrict__ Wa,
                             float* __restrict__ hpp) {
    __shared__ float As[16][64];
    __shared__ float Ws[16][64];
    const int n0 = blockIdx.x * 64;
    const int kb = blockIdx.y * 128;
    const int t  = threadIdx.x;
    const int tx = t & 15, ty = t >> 4;
    float c[4][4];
    #pragma unroll
    for (int i = 0; i < 4; ++i)
        #pragma unroll
        for (int j = 0; j < 4; ++j) c[i][j] = 0.f;
    tile_acc(&h[kb], H_, &Wa[(size_t)n0 * (2 * H_) + kb], 2 * H_, 128, t, c, As, Ws);
    float* dst = hpp + (size_t)blockIdx.y * B_ * H_;
    #pragma unroll
    for (int i = 0; i < 4; ++i) {
        const int m = ty * 4 + i;
        #pragma unroll
        for (int j = 0; j < 4; ++j)
            dst[m * H_ + n0 + tx * 4 + j] = c[i][j];
    }
}

__global__ void reduce_hproj(const float* __restrict__ hpp, const float* __restrict__ ba,
                             float* __restrict__ hproj) {
    const int idx = blockIdx.x * 256 + threadIdx.x;
    const int hh = idx & 1023;
    float s = ba[hh];
    #pragma unroll
    for (int c = 0; c < 8; ++c) s += hpp[(size_t)c * B_ * H_ + idx];
    hproj[idx] = s;
}

// ---------------------------------------------------------------------------
// Gate GEMMs split-K: grid (48 ntiles, 7 chunks of 512) -> P[7][64][3072]
// ---------------------------------------------------------------------------
__global__ void gates_splitk(const float* __restrict__ emb, const float* __restrict__ z,
                             const float* __restrict__ ctx, const float* __restrict__ h,
                             const float* __restrict__ Wx, const float* __restrict__ Wz,
                             const float* __restrict__ Wc, const float* __restrict__ Wh,
                             float* __restrict__ P) {
    __shared__ float As[16][64];
    __shared__ float Ws[16][64];
    const int n0 = blockIdx.x * 64;
    const int yc = blockIdx.y;
    const int t  = threadIdx.x;
    const int tx = t & 15, ty = t >> 4;

    const float* A; const float* W; int lda, kb;
    if (yc == 0)      { A = emb; W = Wx; lda = E_; kb = 0; }
    else if (yc <= 2) { A = z;   W = Wz; lda = H_; kb = (yc - 1) * 512; }
    else if (yc <= 4) { A = ctx; W = Wc; lda = H_; kb = (yc - 3) * 512; }
    else              { A = h;   W = Wh; lda = H_; kb = (yc - 5) * 512; }

    float c[4][4];
    #pragma unroll
    for (int i = 0; i < 4; ++i)
        #pragma unroll
        for (int j = 0; j < 4; ++j) c[i][j] = 0.f;
    tile_acc(&A[kb], lda, &W[(size_t)n0 * lda + kb], lda, 512, t, c, As, Ws);
    float* dst = P + (size_t)yc * B_ * H3_;
    #pragma unroll
    for (int i = 0; i < 4; ++i) {
        const int m = ty * 4 + i;
        #pragma unroll
        for (int j = 0; j < 4; ++j)
            dst[m * H3_ + n0 + tx * 4 + j] = c[i][j];
    }
}

// ---------------------------------------------------------------------------
// bf16 MFMA energy+scores (128x128 tile, 4 waves, 16x16x32, swizzled LDS)
// ---------------------------------------------------------------------------
__global__ __launch_bounds__(256) void energy_mfma(
    const unsigned short* __restrict__ Ab, const unsigned short* __restrict__ Bb,
    const float* __restrict__ hproj, const float* __restrict__ v,
    float* __restrict__ partials) {
    __shared__ unsigned short As[128 * 32];
    __shared__ unsigned short Bs[128 * 32];
    const int nb = blockIdx.x;
    const int mb = blockIdx.y;
    const int m0 = mb * 128, n0 = nb * 128;
    const int t = threadIdx.x;
    const int lane = t & 63, w = t >> 6;
    const int wr = w >> 1, wc = w & 1;

    f32x4 acc[4][4];
    #pragma unroll
    for (int i = 0; i < 4; ++i)
        #pragma unroll
        for (int j = 0; j < 4; ++j) acc[i][j] = (f32x4){0.f, 0.f, 0.f, 0.f};

    for (int k0 = 0; k0 < H_; k0 += 32) {
        #pragma unroll
        for (int r = 0; r < 2; ++r) {
            const int c = r * 256 + t;
            const int row = c >> 2, slot = c & 3;
            const int sw = slot ^ ((row >> 1) & 3);
            uint4 da = *(const uint4*)&Ab[(size_t)(m0 + row) * H_ + k0 + slot * 8];
            *(uint4*)((char*)As + row * 64 + sw * 16) = da;
            uint4 db = *(const uint4*)&Bb[(size_t)(n0 + row) * H_ + k0 + slot * 8];
            *(uint4*)((char*)Bs + row * 64 + sw * 16) = db;
        }
        __syncthreads();
        bf16x8 a[4], b[4];
        #pragma unroll
        for (int i = 0; i < 4; ++i) {
            const int row = wr * 64 + i * 16 + (lane & 15);
            const int sw = (lane >> 4) ^ ((row >> 1) & 3);
            a[i] = *(const bf16x8*)((const char*)As + row * 64 + sw * 16);
        }
        #pragma unroll
        for (int j = 0; j < 4; ++j) {
            const int row = wc * 64 + j * 16 + (lane & 15);
            const int sw = (lane >> 4) ^ ((row >> 1) & 3);
            b[j] = *(const bf16x8*)((const char*)Bs + row * 64 + sw * 16);
        }
        #pragma unroll
        for (int i = 0; i < 4; ++i)
            #pragma unroll
            for (int j = 0; j < 4; ++j)
                acc[i][j] = __builtin_amdgcn_mfma_f32_16x16x32_bf16(a[i], b[j], acc[i][j], 0, 0, 0);
        __syncthreads();
    }

    float vj[4];
    #pragma unroll
    for (int j = 0; j < 4; ++j) vj[j] = v[n0 + wc * 64 + j * 16 + (lane & 15)];

    const int s = mb * 2 + wr;
    #pragma unroll
    for (int i = 0; i < 4; ++i) {
        #pragma unroll
        for (int q = 0; q < 4; ++q) {
            const int b = i * 16 + (lane >> 4) * 4 + q;
            float sum = 0.f;
            #pragma unroll
            for (int j = 0; j < 4; ++j) {
                const int n = n0 + wc * 64 + j * 16 + (lane & 15);
                sum += vj[j] * tanhf(acc[i][j][q] + hproj[b * H_ + n]);
            }
            sum += __shfl_xor(sum, 1);
            sum += __shfl_xor(sum, 2);
            sum += __shfl_xor(sum, 4);
            sum += __shfl_xor(sum, 8);
            if ((lane & 15) == 0)
                partials[((size_t)b * S_ + s) * NT_ + nb * 2 + wc] = sum;
        }
    }
}

// fp32 fallback energy (only if ws too small)
__global__ void energy_scores(const float* __restrict__ enc, const float* __restrict__ Wa,
                              const float* __restrict__ hproj, const float* __restrict__ v,
                              float* __restrict__ partials) {
    __shared__ float As[16][64];
    __shared__ float Ws[16][64];
    __shared__ float red[64][16];
    const int nt = blockIdx.x;
    const int s  = blockIdx.y;
    const int n0 = nt * 64;
    const float* Arow = enc + (size_t)s * (B_ * H_);
    const int t  = threadIdx.x;
    const int tx = t & 15, ty = t >> 4;
    float c[4][4];
    #pragma unroll
    for (int i = 0; i < 4; ++i)
        #pragma unroll
        for (int j = 0; j < 4; ++j) c[i][j] = 0.f;
    tile_acc(Arow, H_, &Wa[(size_t)n0 * (2 * H_) + H_], 2 * H_, H_, t, c, As, Ws);
    #pragma unroll
    for (int i = 0; i < 4; ++i) {
        const int b = ty * 4 + i;
        float part = 0.f;
        #pragma unroll
        for (int j = 0; j < 4; ++j) {
            const int h = n0 + tx * 4 + j;
            part += v[h] * tanhf(c[i][j] + hproj[b * H_ + h]);
        }
        red[b][tx] = part;
    }
    __syncthreads();
    if (t < 64) {
        float sum = 0.f;
        #pragma unroll
        for (int x = 0; x < 16; ++x) sum += red[t][x];
        partials[((size_t)t * S_ + s) * NT_ + nt] = sum;
    }
}

__global__ void softmax_attn(const float* __restrict__ partials, float* __restrict__ attn_out) {
    __shared__ float red[128];
    const int b = blockIdx.x;
    const int s = threadIdx.x;
    float sc = 0.f;
    #pragma unroll
    for (int nt = 0; nt < NT_; ++nt) sc += partials[((size_t)b * S_ + s) * NT_ + nt];
    red[s] = sc; __syncthreads();
    for (int o = 64; o > 0; o >>= 1) {
        if (s < o) red[s] = fmaxf(red[s], red[s + o]);
        __syncthreads();
    }
    const float mx = red[0]; __syncthreads();
    const float e = expf(sc - mx);
    red[s] = e; __syncthreads();
    for (int o = 64; o > 0; o >>= 1) {
        if (s < o) red[s] += red[s + o];
        __syncthreads();
    }
    attn_out[b * S_ + s] = e / red[0];
}

__global__ void context_k(const float* __restrict__ attn, const float* __restrict__ enc,
                          float* __restrict__ ctx) {
    __shared__ float aw[S_];
    const int b = blockIdx.y;
    const int h = blockIdx.x * 256 + threadIdx.x;
    if (threadIdx.x < S_) aw[threadIdx.x] = attn[b * S_ + threadIdx.x];
    __syncthreads();
    float acc = 0.f;
    for (int s = 0; s < S_; ++s)
        acc += aw[s] * enc[((size_t)s * B_ + b) * H_ + h];
    ctx[b * H_ + h] = acc;
}

__global__ void gru_k(const float* __restrict__ P, const float* __restrict__ hlast,
                      const float* __restrict__ bx, const float* __restrict__ bz,
                      const float* __restrict__ bc, const float* __restrict__ bh,
                      float* __restrict__ hnew) {
    const int idx = blockIdx.x * 256 + threadIdx.x;
    const int b = idx >> 10, h = idx & 1023;
    float x[3], hg[3];
    #pragma unroll
    for (int g = 0; g < 3; ++g) {
        const int col = g * H_ + h;
        float sx = bx[col] + bz[col] + bc[col];
        #pragma unroll
        for (int c = 0; c < 5; ++c) sx += P[((size_t)c * B_ + b) * H3_ + col];
        float sh = bh[col];
        #pragma unroll
        for (int c = 5; c < 7; ++c) sh += P[((size_t)c * B_ + b) * H3_ + col];
        x[g] = sx; hg[g] = sh;
    }
    const float r = 1.f / (1.f + expf(-(x[0] + hg[0])));
    const float u = 1.f / (1.f + expf(-(x[1] + hg[1])));
    const float n = tanhf(x[2] + r * hg[2]);
    hnew[idx] = (1.f - u) * n + u * hlast[idx];
}

extern "C" void kernel_launch(void* const* d_in, const int* in_sizes, int n_in,
                              void* d_out, int out_size, void* d_ws, size_t ws_size,
                              hipStream_t stream) {
    const float* emb   = (const float*)d_in[0];
    const float* hid   = (const float*)d_in[1];
    const float* enc   = (const float*)d_in[2];
    const float* z     = (const float*)d_in[3];
    const float* Wa    = (const float*)d_in[4];
    const float* ba    = (const float*)d_in[5];
    const float* v     = (const float*)d_in[6];
    const float* Wx    = (const float*)d_in[7];
    const float* bx    = (const float*)d_in[8];
    const float* Wh    = (const float*)d_in[9];
    const float* bh    = (const float*)d_in[10];
    const float* Wc    = (const float*)d_in[11];
    const float* bc    = (const float*)d_in[12];
    const float* Wz    = (const float*)d_in[13];
    const float* bz    = (const float*)d_in[14];
    const float* Wout  = (const float*)d_in[15];
    const float* bout  = (const float*)d_in[16];

    float* out  = (float*)d_out;
    float* hnew = out + (size_t)B_ * V_;
    float* attn = hnew + (size_t)B_ * H_;

    // ws: [hproj 64K][spart 128K][ctx 64K][union: encb+wa2b | hpp | P+hnewb]
    float* hproj = (float*)d_ws;
    float* spart = hproj + (size_t)B_ * H_;
    float* ctx   = spart + (size_t)B_ * S_ * NT_;
    float* uni   = ctx + (size_t)B_ * H_;
    unsigned short* encb = (unsigned short*)uni;
    unsigned short* wa2b = encb + (size_t)S_ * B_ * H_;
    float* hpp   = uni;                                  // pre-energy (aliases encb)
    float* P     = uni;                                  // post-energy (aliases encb)
    unsigned short* hnewb = (unsigned short*)(P + (size_t)7 * B_ * H3_);
    const size_t need = (size_t)((char*)(wa2b + (size_t)H_ * H_) - (char*)d_ws);

    const float* hlast = hid;
    dim3 blk(256);

    hproj_splitk<<<dim3(H_ / 64, 8), blk, 0, stream>>>(hlast, Wa, hpp);
    reduce_hproj<<<dim3((B_ * H_) / 256), blk, 0, stream>>>(hpp, ba, hproj);

    const bool fast = (ws_size >= need);
    if (fast) {
        cast_bf16<<<dim3((S_ * B_ * H_) / (256 * 8)), blk, 0, stream>>>(enc, encb);
        cast_wa2<<<dim3((H_ * H_) / (256 * 8)), blk, 0, stream>>>(Wa, wa2b);
        energy_mfma<<<dim3(H_ / 128, (S_ * B_) / 128), blk, 0, stream>>>(encb, wa2b, hproj, v, spart);
    } else {
        energy_scores<<<dim3(NT_, S_), blk, 0, stream>>>(enc, Wa, hproj, v, spart);
    }

    softmax_attn<<<dim3(B_), dim3(S_), 0, stream>>>(spart, attn);
    context_k<<<dim3(H_ / 256, B_), blk, 0, stream>>>(attn, enc, ctx);

    gates_splitk<<<dim3(H3_ / 64, 7), blk, 0, stream>>>(emb, z, ctx, hlast,
                                                        Wx, Wz, Wc, Wh, P);
    gru_k<<<dim3((B_ * H_) / 256), blk, 0, stream>>>(P, hlast, bx, bz, bc, bh, hnew);

    if (fast) {
        cast_bf16<<<dim3((B_ * H_) / (256 * 8)), blk, 0, stream>>>(hnew, hnewb);
        wout_mfma<<<dim3(V_ / 64), blk, 0, stream>>>(hnewb, Wout, bout, out);
    } else {
        gemm_nt<<<dim3(V_ / 64), blk, 0, stream>>>(hnew, Wout, bout, out, V_, H_);
    }
}

// Round 5
// 141.965 us; speedup vs baseline: 4.2096x; 1.0394x over previous
//
#include <hip/hip_runtime.h>
#include <hip/hip_bf16.h>
#include <math.h>

#define B_  64
#define S_  128
#define E_  512
#define H_  1024
#define V_  32000
#define H3_ 3072
#define NT_ 16

typedef __attribute__((ext_vector_type(8))) short bf16x8;
typedef __attribute__((ext_vector_type(4))) float f32x4;

__device__ __forceinline__ unsigned short f2b(float f) {
    unsigned int u = __builtin_bit_cast(unsigned int, f);
    u = (u + 0x7fffu + ((u >> 16) & 1u)) >> 16;
    return (unsigned short)u;
}

// ---------------------------------------------------------------------------
// fp32 64x64-tile inner product over a K span
// ---------------------------------------------------------------------------
__device__ __forceinline__ void tile_acc(const float* __restrict__ A, int lda,
                                         const float* __restrict__ Wrow0, int ldw,
                                         int kspan, int t, float c[4][4],
                                         float (*As)[64], float (*Ws)[64]) {
    const int tx = t & 15, ty = t >> 4;
    const int lm = t >> 2;
    const int lk = (t & 3) * 4;
    for (int k0 = 0; k0 < kspan; k0 += 16) {
        float4 av = *(const float4*)&A[lm * lda + k0 + lk];
        float4 wv = *(const float4*)&Wrow0[(size_t)lm * ldw + k0 + lk];
        As[lk + 0][lm] = av.x; As[lk + 1][lm] = av.y;
        As[lk + 2][lm] = av.z; As[lk + 3][lm] = av.w;
        Ws[lk + 0][lm] = wv.x; Ws[lk + 1][lm] = wv.y;
        Ws[lk + 2][lm] = wv.z; Ws[lk + 3][lm] = wv.w;
        __syncthreads();
        #pragma unroll
        for (int k = 0; k < 16; ++k) {
            float4 a = *(const float4*)&As[k][ty * 4];
            float4 w = *(const float4*)&Ws[k][tx * 4];
            c[0][0] += a.x * w.x; c[0][1] += a.x * w.y; c[0][2] += a.x * w.z; c[0][3] += a.x * w.w;
            c[1][0] += a.y * w.x; c[1][1] += a.y * w.y; c[1][2] += a.y * w.z; c[1][3] += a.y * w.w;
            c[2][0] += a.z * w.x; c[2][1] += a.z * w.y; c[2][2] += a.z * w.z; c[2][3] += a.z * w.w;
            c[3][0] += a.w * w.x; c[3][1] += a.w * w.y; c[3][2] += a.w * w.z; c[3][3] += a.w * w.w;
        }
        __syncthreads();
    }
}

__device__ __forceinline__ void hproj_body(int bx, int by, const float* __restrict__ h,
                                           const float* __restrict__ Wa, float* __restrict__ hpp,
                                           int t, float (*As)[64], float (*Ws)[64]) {
    const int n0 = bx * 64;
    const int kb = by * 128;
    const int tx = t & 15, ty = t >> 4;
    float c[4][4];
    #pragma unroll
    for (int i = 0; i < 4; ++i)
        #pragma unroll
        for (int j = 0; j < 4; ++j) c[i][j] = 0.f;
    tile_acc(&h[kb], H_, &Wa[(size_t)n0 * (2 * H_) + kb], 2 * H_, 128, t, c, As, Ws);
    float* dst = hpp + (size_t)by * B_ * H_;
    #pragma unroll
    for (int i = 0; i < 4; ++i) {
        const int m = ty * 4 + i;
        #pragma unroll
        for (int j = 0; j < 4; ++j)
            dst[m * H_ + n0 + tx * 4 + j] = c[i][j];
    }
}

// ---------------------------------------------------------------------------
// Fused prologue: [0,4096) cast enc -> bf16 ; [4096,4608) cast Wa2 -> bf16 ;
// [4608,4736) hproj split-K partials. All independent -> overlap.
// ---------------------------------------------------------------------------
__global__ __launch_bounds__(256) void prologue(
    const float* __restrict__ enc, const float* __restrict__ Wa,
    const float* __restrict__ h, unsigned short* __restrict__ encb,
    unsigned short* __restrict__ wa2b, float* __restrict__ hpp) {
    __shared__ float As[16][64];
    __shared__ float Ws[16][64];
    const int bid = blockIdx.x;
    const int t = threadIdx.x;
    if (bid < 4096) {
        const size_t i8 = ((size_t)bid * 256 + t) * 8;
        float4 a = *(const float4*)&enc[i8];
        float4 b = *(const float4*)&enc[i8 + 4];
        unsigned short o[8] = { f2b(a.x), f2b(a.y), f2b(a.z), f2b(a.w),
                                f2b(b.x), f2b(b.y), f2b(b.z), f2b(b.w) };
        *(uint4*)&encb[i8] = *(uint4*)o;
    } else if (bid < 4608) {
        const int id = (bid - 4096) * 256 + t;
        const int n = id >> 7;
        const int kk = (id & 127) * 8;
        const float* src = &Wa[(size_t)n * (2 * H_) + H_ + kk];
        float4 a = *(const float4*)src;
        float4 b = *(const float4*)(src + 4);
        unsigned short o[8] = { f2b(a.x), f2b(a.y), f2b(a.z), f2b(a.w),
                                f2b(b.x), f2b(b.y), f2b(b.z), f2b(b.w) };
        *(uint4*)&wa2b[(size_t)n * H_ + kk] = *(uint4*)o;
    } else {
        const int id = bid - 4608;
        hproj_body(id & 15, id >> 4, h, Wa, hpp, t, As, Ws);
    }
}

// standalone hproj (fallback path)
__global__ void hproj_splitk(const float* __restrict__ h, const float* __restrict__ Wa,
                             float* __restrict__ hpp) {
    __shared__ float As[16][64];
    __shared__ float Ws[16][64];
    hproj_body(blockIdx.x, blockIdx.y, h, Wa, hpp, threadIdx.x, As, Ws);
}

__global__ void reduce_hproj(const float* __restrict__ hpp, const float* __restrict__ ba,
                             float* __restrict__ hproj) {
    const int idx = blockIdx.x * 256 + threadIdx.x;
    const int hh = idx & 1023;
    float s = ba[hh];
    #pragma unroll
    for (int c = 0; c < 8; ++c) s += hpp[(size_t)c * B_ * H_ + idx];
    hproj[idx] = s;
}

// ---------------------------------------------------------------------------
// bf16 MFMA energy+scores (128x128 tile, 4 waves, 16x16x32, swizzled LDS)
// ---------------------------------------------------------------------------
__global__ __launch_bounds__(256) void energy_mfma(
    const unsigned short* __restrict__ Ab, const unsigned short* __restrict__ Bb,
    const float* __restrict__ hproj, const float* __restrict__ v,
    float* __restrict__ partials) {
    __shared__ unsigned short As[128 * 32];
    __shared__ unsigned short Bs[128 * 32];
    const int nb = blockIdx.x;
    const int mb = blockIdx.y;
    const int m0 = mb * 128, n0 = nb * 128;
    const int t = threadIdx.x;
    const int lane = t & 63, w = t >> 6;
    const int wr = w >> 1, wc = w & 1;

    f32x4 acc[4][4];
    #pragma unroll
    for (int i = 0; i < 4; ++i)
        #pragma unroll
        for (int j = 0; j < 4; ++j) acc[i][j] = (f32x4){0.f, 0.f, 0.f, 0.f};

    for (int k0 = 0; k0 < H_; k0 += 32) {
        #pragma unroll
        for (int r = 0; r < 2; ++r) {
            const int c = r * 256 + t;
            const int row = c >> 2, slot = c & 3;
            const int sw = slot ^ ((row >> 1) & 3);
            uint4 da = *(const uint4*)&Ab[(size_t)(m0 + row) * H_ + k0 + slot * 8];
            *(uint4*)((char*)As + row * 64 + sw * 16) = da;
            uint4 db = *(const uint4*)&Bb[(size_t)(n0 + row) * H_ + k0 + slot * 8];
            *(uint4*)((char*)Bs + row * 64 + sw * 16) = db;
        }
        __syncthreads();
        bf16x8 a[4], b[4];
        #pragma unroll
        for (int i = 0; i < 4; ++i) {
            const int row = wr * 64 + i * 16 + (lane & 15);
            const int sw = (lane >> 4) ^ ((row >> 1) & 3);
            a[i] = *(const bf16x8*)((const char*)As + row * 64 + sw * 16);
        }
        #pragma unroll
        for (int j = 0; j < 4; ++j) {
            const int row = wc * 64 + j * 16 + (lane & 15);
            const int sw = (lane >> 4) ^ ((row >> 1) & 3);
            b[j] = *(const bf16x8*)((const char*)Bs + row * 64 + sw * 16);
        }
        #pragma unroll
        for (int i = 0; i < 4; ++i)
            #pragma unroll
            for (int j = 0; j < 4; ++j)
                acc[i][j] = __builtin_amdgcn_mfma_f32_16x16x32_bf16(a[i], b[j], acc[i][j], 0, 0, 0);
        __syncthreads();
    }

    float vj[4];
    #pragma unroll
    for (int j = 0; j < 4; ++j) vj[j] = v[n0 + wc * 64 + j * 16 + (lane & 15)];

    const int s = mb * 2 + wr;
    #pragma unroll
    for (int i = 0; i < 4; ++i) {
        #pragma unroll
        for (int q = 0; q < 4; ++q) {
            const int b = i * 16 + (lane >> 4) * 4 + q;
            float sum = 0.f;
            #pragma unroll
            for (int j = 0; j < 4; ++j) {
                const int n = n0 + wc * 64 + j * 16 + (lane & 15);
                sum += vj[j] * tanhf(acc[i][j][q] + hproj[b * H_ + n]);
            }
            sum += __shfl_xor(sum, 1);
            sum += __shfl_xor(sum, 2);
            sum += __shfl_xor(sum, 4);
            sum += __shfl_xor(sum, 8);
            if ((lane & 15) == 0)
                partials[((size_t)b * S_ + s) * NT_ + nb * 2 + wc] = sum;
        }
    }
}

// fp32 fallback energy (only if ws too small)
__global__ void energy_scores(const float* __restrict__ enc, const float* __restrict__ Wa,
                              const float* __restrict__ hproj, const float* __restrict__ v,
                              float* __restrict__ partials) {
    __shared__ float As[16][64];
    __shared__ float Ws[16][64];
    __shared__ float red[64][16];
    const int nt = blockIdx.x;
    const int s  = blockIdx.y;
    const int n0 = nt * 64;
    const float* Arow = enc + (size_t)s * (B_ * H_);
    const int t  = threadIdx.x;
    const int tx = t & 15, ty = t >> 4;
    float c[4][4];
    #pragma unroll
    for (int i = 0; i < 4; ++i)
        #pragma unroll
        for (int j = 0; j < 4; ++j) c[i][j] = 0.f;
    tile_acc(Arow, H_, &Wa[(size_t)n0 * (2 * H_) + H_], 2 * H_, H_, t, c, As, Ws);
    #pragma unroll
    for (int i = 0; i < 4; ++i) {
        const int b = ty * 4 + i;
        float part = 0.f;
        #pragma unroll
        for (int j = 0; j < 4; ++j) {
            const int h = n0 + tx * 4 + j;
            part += v[h] * tanhf(c[i][j] + hproj[b * H_ + h]);
        }
        red[b][tx] = part;
    }
    __syncthreads();
    if (t < 64) {
        float sum = 0.f;
        #pragma unroll
        for (int x = 0; x < 16; ++x) sum += red[t][x];
        partials[((size_t)t * S_ + s) * NT_ + nt] = sum;
    }
}

// ---------------------------------------------------------------------------
// Fused softmax + context: blockIdx.y = b, blockIdx.x = h-quarter.
// ---------------------------------------------------------------------------
__global__ __launch_bounds__(256) void softmax_ctx(
    const float* __restrict__ spart, const float* __restrict__ enc,
    float* __restrict__ attn, float* __restrict__ ctx) {
    __shared__ float red[128];
    __shared__ float aw[128];
    const int b = blockIdx.y;
    const int t = threadIdx.x;
    if (t < 128) {
        float sc = 0.f;
        #pragma unroll
        for (int nt = 0; nt < NT_; ++nt) sc += spart[((size_t)b * S_ + t) * NT_ + nt];
        aw[t] = sc;
        red[t] = sc;
    }
    __syncthreads();
    for (int o = 64; o > 0; o >>= 1) {
        if (t < o) red[t] = fmaxf(red[t], red[t + o]);
        __syncthreads();
    }
    const float mx = red[0];
    __syncthreads();
    if (t < 128) { aw[t] = expf(aw[t] - mx); red[t] = aw[t]; }
    __syncthreads();
    for (int o = 64; o > 0; o >>= 1) {
        if (t < o) red[t] += red[t + o];
        __syncthreads();
    }
    const float inv = 1.f / red[0];
    if (t < 128) {
        aw[t] *= inv;
        if (blockIdx.x == 0) attn[b * S_ + t] = aw[t];
    }
    __syncthreads();
    const int h = blockIdx.x * 256 + t;
    float acc = 0.f;
    for (int s = 0; s < S_; ++s)
        acc += aw[s] * enc[((size_t)s * B_ + b) * H_ + h];
    ctx[b * H_ + h] = acc;
}

// ---------------------------------------------------------------------------
// Gate GEMMs split-K: grid (48 ntiles, 7 chunks of 512) -> P[7][64][3072]
// ---------------------------------------------------------------------------
__global__ void gates_splitk(const float* __restrict__ emb, const float* __restrict__ z,
                             const float* __restrict__ ctx, const float* __restrict__ h,
                             const float* __restrict__ Wx, const float* __restrict__ Wz,
                             const float* __restrict__ Wc, const float* __restrict__ Wh,
                             float* __restrict__ P) {
    __shared__ float As[16][64];
    __shared__ float Ws[16][64];
    const int n0 = blockIdx.x * 64;
    const int yc = blockIdx.y;
    const int t  = threadIdx.x;
    const int tx = t & 15, ty = t >> 4;

    const float* A; const float* W; int lda, kb;
    if (yc == 0)      { A = emb; W = Wx; lda = E_; kb = 0; }
    else if (yc <= 2) { A = z;   W = Wz; lda = H_; kb = (yc - 1) * 512; }
    else if (yc <= 4) { A = ctx; W = Wc; lda = H_; kb = (yc - 3) * 512; }
    else              { A = h;   W = Wh; lda = H_; kb = (yc - 5) * 512; }

    float c[4][4];
    #pragma unroll
    for (int i = 0; i < 4; ++i)
        #pragma unroll
        for (int j = 0; j < 4; ++j) c[i][j] = 0.f;
    tile_acc(&A[kb], lda, &W[(size_t)n0 * lda + kb], lda, 512, t, c, As, Ws);
    float* dst = P + (size_t)yc * B_ * H3_;
    #pragma unroll
    for (int i = 0; i < 4; ++i) {
        const int m = ty * 4 + i;
        #pragma unroll
        for (int j = 0; j < 4; ++j)
            dst[m * H3_ + n0 + tx * 4 + j] = c[i][j];
    }
}

// ---------------------------------------------------------------------------
// GRU elementwise (7-way reduce + biases) + fused bf16 cast of h_new
// ---------------------------------------------------------------------------
__global__ void gru_k(const float* __restrict__ P, const float* __restrict__ hlast,
                      const float* __restrict__ bx, const float* __restrict__ bz,
                      const float* __restrict__ bc, const float* __restrict__ bh,
                      float* __restrict__ hnew, unsigned short* __restrict__ hnewb) {
    const int idx = blockIdx.x * 256 + threadIdx.x;
    const int b = idx >> 10, h = idx & 1023;
    float x[3], hg[3];
    #pragma unroll
    for (int g = 0; g < 3; ++g) {
        const int col = g * H_ + h;
        float sx = bx[col] + bz[col] + bc[col];
        #pragma unroll
        for (int c = 0; c < 5; ++c) sx += P[((size_t)c * B_ + b) * H3_ + col];
        float sh = bh[col];
        #pragma unroll
        for (int c = 5; c < 7; ++c) sh += P[((size_t)c * B_ + b) * H3_ + col];
        x[g] = sx; hg[g] = sh;
    }
    const float r = 1.f / (1.f + expf(-(x[0] + hg[0])));
    const float u = 1.f / (1.f + expf(-(x[1] + hg[1])));
    const float n = tanhf(x[2] + r * hg[2]);
    const float val = (1.f - u) * n + u * hlast[idx];
    hnew[idx] = val;
    if (hnewb) hnewb[idx] = f2b(val);
}

// ---------------------------------------------------------------------------
// Wout bf16-MFMA GEMM, W fp32->bf16 converted during LDS staging
// ---------------------------------------------------------------------------
__global__ __launch_bounds__(256) void wout_mfma(
    const unsigned short* __restrict__ Ab, const float* __restrict__ W,
    const float* __restrict__ bias, float* __restrict__ C) {
    __shared__ unsigned short As[64 * 64];
    __shared__ unsigned short Bs[64 * 64];
    const int n0 = blockIdx.x * 64;
    const int t = threadIdx.x;
    const int lane = t & 63, w = t >> 6;
    const int wr = w >> 1, wc = w & 1;

    f32x4 acc[2][2];
    #pragma unroll
    for (int i = 0; i < 2; ++i)
        #pragma unroll
        for (int j = 0; j < 2; ++j) acc[i][j] = (f32x4){0.f, 0.f, 0.f, 0.f};

    for (int k0 = 0; k0 < H_; k0 += 64) {
        #pragma unroll
        for (int r = 0; r < 2; ++r) {
            const int c = r * 256 + t;
            const int row = c >> 3, slot = c & 7;
            const int sw = slot ^ (row & 7);
            uint4 da = *(const uint4*)&Ab[(size_t)row * H_ + k0 + slot * 8];
            *(uint4*)((char*)As + row * 128 + sw * 16) = da;
        }
        #pragma unroll
        for (int r = 0; r < 4; ++r) {
            const int c = r * 256 + t;
            const int row = c >> 4, q4 = c & 15;
            const float4 wv = *(const float4*)&W[(size_t)(n0 + row) * H_ + k0 + q4 * 4];
            uint2 pk;
            pk.x = (unsigned int)f2b(wv.x) | ((unsigned int)f2b(wv.y) << 16);
            pk.y = (unsigned int)f2b(wv.z) | ((unsigned int)f2b(wv.w) << 16);
            const int slot = q4 >> 1, half = q4 & 1;
            const int sw = slot ^ (row & 7);
            *(uint2*)((char*)Bs + row * 128 + sw * 16 + half * 8) = pk;
        }
        __syncthreads();
        #pragma unroll
        for (int kk = 0; kk < 2; ++kk) {
            bf16x8 a[2], b[2];
            #pragma unroll
            for (int i = 0; i < 2; ++i) {
                const int row = wr * 32 + i * 16 + (lane & 15);
                const int sw = (kk * 4 + (lane >> 4)) ^ (row & 7);
                a[i] = *(const bf16x8*)((const char*)As + row * 128 + sw * 16);
            }
            #pragma unroll
            for (int j = 0; j < 2; ++j) {
                const int row = wc * 32 + j * 16 + (lane & 15);
                const int sw = (kk * 4 + (lane >> 4)) ^ (row & 7);
                b[j] = *(const bf16x8*)((const char*)Bs + row * 128 + sw * 16);
            }
            #pragma unroll
            for (int i = 0; i < 2; ++i)
                #pragma unroll
                for (int j = 0; j < 2; ++j)
                    acc[i][j] = __builtin_amdgcn_mfma_f32_16x16x32_bf16(a[i], b[j], acc[i][j], 0, 0, 0);
        }
        __syncthreads();
    }

    #pragma unroll
    for (int i = 0; i < 2; ++i)
        #pragma unroll
        for (int j = 0; j < 2; ++j) {
            const int n = n0 + wc * 32 + j * 16 + (lane & 15);
            const float bn = bias[n];
            #pragma unroll
            for (int q = 0; q < 4; ++q) {
                const int m = wr * 32 + i * 16 + (lane >> 4) * 4 + q;
                C[(size_t)m * V_ + n] = acc[i][j][q] + bn;
            }
        }
}

// fp32 fallback Wout GEMM
__global__ void gemm_nt(const float* __restrict__ A, const float* __restrict__ W,
                        const float* __restrict__ bias, float* __restrict__ C,
                        int N, int K) {
    __shared__ float As[16][64];
    __shared__ float Ws[16][64];
    const int n0 = blockIdx.x * 64;
    const int t  = threadIdx.x;
    const int tx = t & 15, ty = t >> 4;
    float c[4][4];
    #pragma unroll
    for (int i = 0; i < 4; ++i)
        #pragma unroll
        for (int j = 0; j < 4; ++j) c[i][j] = 0.f;
    tile_acc(A, K, &W[(size_t)n0 * K], K, K, t, c, As, Ws);
    #pragma unroll
    for (int i = 0; i < 4; ++i) {
        const int m = ty * 4 + i;
        #pragma unroll
        for (int j = 0; j < 4; ++j) {
            const int n = n0 + tx * 4 + j;
            C[m * N + n] = c[i][j] + bias[n];
        }
    }
}

extern "C" void kernel_launch(void* const* d_in, const int* in_sizes, int n_in,
                              void* d_out, int out_size, void* d_ws, size_t ws_size,
                              hipStream_t stream) {
    const float* emb   = (const float*)d_in[0];
    const float* hid   = (const float*)d_in[1];
    const float* enc   = (const float*)d_in[2];
    const float* z     = (const float*)d_in[3];
    const float* Wa    = (const float*)d_in[4];
    const float* ba    = (const float*)d_in[5];
    const float* v     = (const float*)d_in[6];
    const float* Wx    = (const float*)d_in[7];
    const float* bx    = (const float*)d_in[8];
    const float* Wh    = (const float*)d_in[9];
    const float* bh    = (const float*)d_in[10];
    const float* Wc    = (const float*)d_in[11];
    const float* bc    = (const float*)d_in[12];
    const float* Wz    = (const float*)d_in[13];
    const float* bz    = (const float*)d_in[14];
    const float* Wout  = (const float*)d_in[15];
    const float* bout  = (const float*)d_in[16];

    float* out  = (float*)d_out;
    float* hnew = out + (size_t)B_ * V_;
    float* attn = hnew + (size_t)B_ * H_;

    // ws: [hproj][spart][ctx][hpp][encb|P,hnewb][wa2b]
    float* hproj = (float*)d_ws;
    float* spart = hproj + (size_t)B_ * H_;
    float* ctx   = spart + (size_t)B_ * S_ * NT_;
    float* hpp   = ctx + (size_t)B_ * H_;                 // 512K floats (2 MB)
    float* uni   = hpp + (size_t)8 * B_ * H_;
    unsigned short* encb = (unsigned short*)uni;          // 16.78 MB
    unsigned short* wa2b = encb + (size_t)S_ * B_ * H_;   // 2.1 MB
    float* P = uni;                                       // aliases encb post-energy
    unsigned short* hnewb = (unsigned short*)(P + (size_t)7 * B_ * H3_);
    const size_t need = (size_t)((char*)(wa2b + (size_t)H_ * H_) - (char*)d_ws);

    const float* hlast = hid;
    dim3 blk(256);

    const bool fast = (ws_size >= need);
    if (fast) {
        // casts + hproj split-K fused, all independent
        prologue<<<dim3(4736), blk, 0, stream>>>(enc, Wa, hlast, encb, wa2b, hpp);
        reduce_hproj<<<dim3((B_ * H_) / 256), blk, 0, stream>>>(hpp, ba, hproj);
        energy_mfma<<<dim3(H_ / 128, (S_ * B_) / 128), blk, 0, stream>>>(encb, wa2b, hproj, v, spart);
    } else {
        hproj_splitk<<<dim3(H_ / 64, 8), blk, 0, stream>>>(hlast, Wa, hpp);
        reduce_hproj<<<dim3((B_ * H_) / 256), blk, 0, stream>>>(hpp, ba, hproj);
        energy_scores<<<dim3(NT_, S_), blk, 0, stream>>>(enc, Wa, hproj, v, spart);
    }

    softmax_ctx<<<dim3(H_ / 256, B_), blk, 0, stream>>>(spart, enc, attn, ctx);

    gates_splitk<<<dim3(H3_ / 64, 7), blk, 0, stream>>>(emb, z, ctx, hlast,
                                                        Wx, Wz, Wc, Wh, P);
    gru_k<<<dim3((B_ * H_) / 256), blk, 0, stream>>>(P, hlast, bx, bz, bc, bh,
                                                     hnew, fast ? hnewb : nullptr);

    if (fast) {
        wout_mfma<<<dim3(V_ / 64), blk, 0, stream>>>(hnewb, Wout, bout, out);
    } else {
        gemm_nt<<<dim3(V_ / 64), blk, 0, stream>>>(hnew, Wout, bout, out, V_, H_);
    }
}